// Round 7
// baseline (2615.942 us; speedup 1.0000x reference)
//
#include <hip/hip_runtime.h>
#include <math.h>

#define N_NODES 65536
#define NB 16
#define CBLK 512   // coop grid: 16 segments x 32 chunks; 2 blocks/CU guaranteed resident
#define CPS 32     // chunks per segment

// ---- ws layout (float offsets) ----
#define WD0_OFF   0ull          // dense W0: 128*576 bf16 = 36864 f
#define WD1_OFF   36864ull      // dense W1: 256*1152 bf16 = 147456 f
#define WB0_OFF   184320ull     // padded W0 (fallback): 65536 f
#define WB1_OFF   249856ull     // padded W1 (fallback): 262144 f
#define WTIH_OFF  512000ull     // 512*1024 f   (wT rows 0..511)
#define WTHH_OFF  1036288ull    // 256*1024 f   (wT rows 512..767, contiguous)
#define BIAS_OFF  1298432ull    // 1024 f
#define HLG_OFF   1299456ull    // 16*256 f
#define SEGB_OFF  1303552ull    // 17 ints (+pad to 32)
#define BARS_OFF  1303584ull    // 32 ints (16 barrier slots)
#define PM_OFF    1303616ull    // 512 f
#define PDEN_OFF  1304128ull    // 512 f
#define PNUM_OFF  1304640ull    // 512*256 f = 131072
#define H1_OFF    1435712ull    // N*128 f
#define H2_OFF    9824320ull    // N*256 f
#define AF_OFF    26601536ull   // 65536*1152 bf16 = 37748736 f (split only)
#define SPLIT_NEED_F 64350272ull

typedef __attribute__((ext_vector_type(8))) short s16x8;
typedef __attribute__((ext_vector_type(4))) float f32x4;

__device__ __forceinline__ float sigm(float x) {
  return __builtin_amdgcn_rcpf(1.0f + __expf(-x));
}

__device__ __forceinline__ short f2bf(float f) {
  union { float f; unsigned u; } v; v.f = f;
  unsigned r = (v.u + 0x7FFFu + ((v.u >> 16) & 1u)) >> 16;
  return (short)r;
}

__device__ __forceinline__ void bspline_bases(float x, float b8[8]) {
  float t[12];
#pragma unroll
  for (int i = 0; i < 12; ++i) t[i] = (float)(i - 3) * 0.4f - 1.0f;
  float b[11];
#pragma unroll
  for (int i = 0; i < 11; ++i) b[i] = (x >= t[i] && x < t[i + 1]) ? 1.0f : 0.0f;
#pragma unroll
  for (int k = 1; k <= 3; ++k) {
#pragma unroll
    for (int i = 0; i + k < 11; ++i) {
      float invl = 1.0f / (t[i + k] - t[i]);
      float invr = 1.0f / (t[i + k + 1] - t[i + 1]);
      b[i] = (x - t[i]) * invl * b[i] + (t[i + k + 1] - x) * invr * b[i + 1];
    }
  }
#pragma unroll
  for (int j = 0; j < 8; ++j) b8[j] = b[j];
}

// ---- prep: weights (dense + padded bf16), LSTM wT (f32), bias, barrier slots, segb ----
__global__ __launch_bounds__(256) void prep_kernel(
    const float* __restrict__ bw0, const float* __restrict__ sw0, const float* __restrict__ sc0,
    const float* __restrict__ bw1, const float* __restrict__ sw1, const float* __restrict__ sc1,
    const float* __restrict__ w_ih, const float* __restrict__ w_hh,
    const float* __restrict__ b_ih, const float* __restrict__ b_hh,
    const int* __restrict__ batch,
    float* __restrict__ ws) {
  int id = blockIdx.x * 256 + threadIdx.x;
  if (id < 73728) {                        // Wd0 dense: [128][576]
    int o = id / 576, k = id % 576;
    float v;
    if (k < 64) v = bw0[o * 64 + k];
    else { int kk = k - 64, d = kk >> 3, j = kk & 7;
           v = sw0[(o * 64 + d) * 8 + j] * sc0[o * 64 + d]; }
    ((short*)(ws + WD0_OFF))[id] = f2bf(v);
  } else if (id < 368640) {                // Wd1 dense: [256][1152]
    int l = id - 73728;
    int o = l / 1152, k = l % 1152;
    float v;
    if (k < 128) v = bw1[o * 128 + k];
    else { int kk = k - 128, d = kk >> 3, j = kk & 7;
           v = sw1[(o * 128 + d) * 8 + j] * sc1[o * 128 + d]; }
    ((short*)(ws + WD1_OFF))[l] = f2bf(v);
  } else if (id < 499712) {                // Wp0 padded (fallback)
    int l = id - 368640;
    int o = l >> 10, k = l & 1023, d = k >> 4, j = k & 15;
    float v = (j == 0) ? bw0[o * 64 + d]
            : (j < 9)  ? sw0[(o * 64 + d) * 8 + (j - 1)] * sc0[o * 64 + d] : 0.0f;
    ((short*)(ws + WB0_OFF))[l] = f2bf(v);
  } else if (id < 1024000) {               // Wp1 padded (fallback)
    int l = id - 499712;
    int o = l >> 11, k = l & 2047, d = k >> 4, j = k & 15;
    float v = (j == 0) ? bw1[o * 128 + d]
            : (j < 9)  ? sw1[(o * 128 + d) * 8 + (j - 1)] * sc1[o * 128 + d] : 0.0f;
    ((short*)(ws + WB1_OFF))[l] = f2bf(v);
  } else if (id < 1548288) {
    int l = id - 1024000; int k = l >> 10, g = l & 1023;
    ws[WTIH_OFF + l] = w_ih[g * 512 + k];
  } else if (id < 1810432) {
    int l = id - 1548288; int k = l >> 10, g = l & 1023;
    ws[WTHH_OFF + l] = w_hh[g * 256 + k];
  } else if (id < 1811456) {
    int g = id - 1810432;
    ws[BIAS_OFF + g] = b_ih[g] + b_hh[g];
  } else if (id < 1811488) {
    ((int*)(ws + BARS_OFF))[id - 1811456] = 0;   // barrier slots MUST be zeroed each launch
  } else if (id < 1811505) {
    int s = id - 1811488;
    int lo = 0, hi = N_NODES;
    while (lo < hi) { int mid = (lo + hi) >> 1; if (batch[mid] < s) lo = mid + 1; else hi = mid; }
    ((int*)(ws + SEGB_OFF))[s] = lo;
  }
}

// ---- expansion: x[N][IN] f32 -> Af[N][9*IN] bf16 dense ----
template <int IN>
__global__ __launch_bounds__(256) void expand_kernel(const float* __restrict__ in,
                                                     short* __restrict__ Af) {
  constexpr int RS = 9 * IN;
  const int total = N_NODES * IN;
  for (int id = blockIdx.x * 256 + threadIdx.x; id < total; id += gridDim.x * 256) {
    int n = id / IN;
    int d = id & (IN - 1);
    float v = in[id];
    float sv = v * sigm(v);
    float b8[8];
    bspline_bases(v, b8);
    short* rowp = Af + (size_t)n * RS;
    rowp[d] = f2bf(sv);
    s16x8 q;
#pragma unroll
    for (int j = 0; j < 8; ++j) q[j] = f2bf(b8[j]);
    ((s16x8*)(rowp + IN))[d] = q;
  }
}

// ---- pure GEMM: out[N][OUT] = A[N][K]bf16 @ W[OUT][K]bf16^T. BK=96, 128x128 tile ----
template <int K, int OUT>
__global__ __launch_bounds__(256, 2) void gemm_mfma(const short* __restrict__ A,
                                                    const short* __restrict__ Wp,
                                                    float* __restrict__ out) {
  constexpr int CHUNKS = K / 96;
  __shared__ s16x8 As[1536];
  __shared__ s16x8 Bs[1536];
  const int tid = threadIdx.x;
  const int n0 = blockIdx.x * 128;
  const int nb0 = blockIdx.y * 128;
  const int lane = tid & 63;
  const int wid = tid >> 6;
  const int wr = wid >> 1, wc = wid & 1;
  const int l15 = lane & 15, l4 = lane >> 4;

  f32x4 acc[4][4] = {};

  for (int c = 0; c < CHUNKS; ++c) {
    if (c) __syncthreads();
    const short* abase = A + (size_t)n0 * K + c * 96;
    const short* bbase = Wp + (size_t)nb0 * K + c * 96;
#pragma unroll
    for (int i = 0; i < 6; ++i) {
      int s = i * 256 + tid;
      int kg = s >> 7, row = s & 127;
      __builtin_amdgcn_global_load_lds(
          (const __attribute__((address_space(1))) unsigned int*)(abase + (size_t)row * K + kg * 8),
          (__attribute__((address_space(3))) unsigned int*)&As[s], 16, 0, 0);
      __builtin_amdgcn_global_load_lds(
          (const __attribute__((address_space(1))) unsigned int*)(bbase + (size_t)row * K + kg * 8),
          (__attribute__((address_space(3))) unsigned int*)&Bs[s], 16, 0, 0);
    }
    __syncthreads();
#pragma unroll
    for (int kk = 0; kk < 3; ++kk) {
      s16x8 a[4], b[4];
#pragma unroll
      for (int mi = 0; mi < 4; ++mi)
        a[mi] = As[(kk * 4 + l4) * 128 + wr * 64 + mi * 16 + l15];
#pragma unroll
      for (int ni = 0; ni < 4; ++ni)
        b[ni] = Bs[(kk * 4 + l4) * 128 + wc * 64 + ni * 16 + l15];
#pragma unroll
      for (int mi = 0; mi < 4; ++mi)
#pragma unroll
        for (int ni = 0; ni < 4; ++ni)
          acc[mi][ni] = __builtin_amdgcn_mfma_f32_16x16x32_bf16(a[mi], b[ni], acc[mi][ni], 0, 0, 0);
    }
  }
#pragma unroll
  for (int mi = 0; mi < 4; ++mi) {
#pragma unroll
    for (int r = 0; r < 4; ++r) {
      int m = wr * 64 + mi * 16 + l4 * 4 + r;
      float* orow = out + (size_t)(n0 + m) * OUT + nb0;
#pragma unroll
      for (int ni = 0; ni < 4; ++ni)
        orow[wc * 64 + ni * 16 + l15] = acc[mi][ni][r];
    }
  }
}

// ---- fused KAN (fallback when ws too small) ----
template <int IN, int OUT>
__global__ __launch_bounds__(256, 2) void kan_mfma(const float* __restrict__ in,
                                                   const short* __restrict__ Wp,
                                                   float* __restrict__ out) {
  constexpr int Kp = IN * 16;
  constexpr int CHUNKS = Kp / 128;
  __shared__ s16x8 As[2048];
  __shared__ s16x8 Bs[2048];
  const int tid = threadIdx.x;
  const int n0 = blockIdx.x * 128;
  const int nb0 = blockIdx.y * 128;
  const int lane = tid & 63;
  const int wid = tid >> 6;
  const int wr = wid >> 1, wc = wid & 1;
  const int l15 = lane & 15, l4 = lane >> 4;
  const int xn = tid & 127, dh = tid >> 7;

  f32x4 acc[4][4] = {};

  for (int c = 0; c < CHUNKS; ++c) {
    if (c) __syncthreads();
    const short* wbase = Wp + (size_t)nb0 * Kp + c * 128;
#pragma unroll
    for (int i = 0; i < 8; ++i) {
      int s = i * 256 + tid;
      int kg = s >> 7, col = s & 127;
      const short* src = wbase + (size_t)col * Kp + kg * 8;
      __builtin_amdgcn_global_load_lds(
          (const __attribute__((address_space(1))) unsigned int*)src,
          (__attribute__((address_space(3))) unsigned int*)&Bs[s], 16, 0, 0);
    }
#pragma unroll
    for (int i = 0; i < 4; ++i) {
      int dl = i * 2 + dh;
      float v = in[(size_t)(n0 + xn) * IN + (c * 8 + dl)];
      float sv = v * sigm(v);
      float b8[8];
      bspline_bases(v, b8);
      s16x8 q0, q1 = {};
      q0[0] = f2bf(sv);
      q0[1] = f2bf(b8[0]); q0[2] = f2bf(b8[1]); q0[3] = f2bf(b8[2]);
      q0[4] = f2bf(b8[3]); q0[5] = f2bf(b8[4]); q0[6] = f2bf(b8[5]);
      q0[7] = f2bf(b8[6]);
      q1[0] = f2bf(b8[7]);
      As[(dl * 2) * 128 + xn] = q0;
      As[(dl * 2 + 1) * 128 + xn] = q1;
    }
    __syncthreads();
#pragma unroll
    for (int kk = 0; kk < 4; ++kk) {
      s16x8 a[4], b[4];
#pragma unroll
      for (int mi = 0; mi < 4; ++mi)
        a[mi] = As[(kk * 4 + l4) * 128 + wr * 64 + mi * 16 + l15];
#pragma unroll
      for (int ni = 0; ni < 4; ++ni)
        b[ni] = Bs[(kk * 4 + l4) * 128 + wc * 64 + ni * 16 + l15];
#pragma unroll
      for (int mi = 0; mi < 4; ++mi)
#pragma unroll
        for (int ni = 0; ni < 4; ++ni)
          acc[mi][ni] = __builtin_amdgcn_mfma_f32_16x16x32_bf16(a[mi], b[ni], acc[mi][ni], 0, 0, 0);
    }
  }
#pragma unroll
  for (int mi = 0; mi < 4; ++mi) {
#pragma unroll
    for (int r = 0; r < 4; ++r) {
      int m = wr * 64 + mi * 16 + l4 * 4 + r;
      float* orow = out + (size_t)(n0 + m) * OUT + nb0;
#pragma unroll
      for (int ni = 0; ni < 4; ++ni)
        orow[wc * 64 + ni * 16 + l15] = acc[mi][ni][r];
    }
  }
}

// ---- LayerNorm over 256 dims, one wave per node, in place ----
__global__ __launch_bounds__(256) void ln_kernel(float* __restrict__ h,
                                                 const float* __restrict__ g,
                                                 const float* __restrict__ b) {
  int gid = blockIdx.x * 256 + threadIdx.x;
  int node = gid >> 6;
  int lane = gid & 63;
  float4* row = (float4*)(h + (size_t)node * 256);
  float4 v = row[lane];
  float s1 = v.x + v.y + v.z + v.w;
  float s2 = v.x * v.x + v.y * v.y + v.z * v.z + v.w * v.w;
#pragma unroll
  for (int off = 32; off; off >>= 1) { s1 += __shfl_xor(s1, off); s2 += __shfl_xor(s2, off); }
  float mu = s1 * (1.0f / 256.0f);
  float var = s2 * (1.0f / 256.0f) - mu * mu;
  float rs = rsqrtf(var + 1e-5f);
  float4 g4 = ((const float4*)g)[lane];
  float4 b4 = ((const float4*)b)[lane];
  v.x = (v.x - mu) * rs * g4.x + b4.x;
  v.y = (v.y - mu) * rs * g4.y + b4.y;
  v.z = (v.z - mu) * rs * g4.z + b4.z;
  v.w = (v.w - mu) * rs * g4.w + b4.w;
  row[lane] = v;
}

// ---- device-scope grid barrier: monotonic slot, release-add / acquire-spin.
//      Safe: 512 blocks x launch_bounds(256,2) => all co-resident (2 blocks/CU). ----
__device__ __forceinline__ void gridbar(int* slot) {
  __syncthreads();
  if (threadIdx.x == 0) {
    __hip_atomic_fetch_add(slot, 1, __ATOMIC_RELEASE, __HIP_MEMORY_SCOPE_AGENT);
    while (__hip_atomic_load(slot, __ATOMIC_ACQUIRE, __HIP_MEMORY_SCOPE_AGENT) < CBLK)
      __builtin_amdgcn_s_sleep(8);
  }
  __syncthreads();
}

// ---- fused set2set: 8 x { merge(prev r) + LSTM | bar | attn partials | bar } + output ----
__global__ __launch_bounds__(256, 2) void set2set_coop(
    const float* __restrict__ h, const int* __restrict__ segb,
    const float* __restrict__ wT, const float* __restrict__ bias,
    float* __restrict__ hl_g, float* __restrict__ pm,
    float* __restrict__ pden, float* __restrict__ pnum,
    int* bars, float* __restrict__ out) {
  const int blk = blockIdx.x;
  const int t = threadIdx.x;
  __shared__ float Xl[768];           // [h | r | h] LSTM input
  __shared__ float gl[256];           // gate exchange
  __shared__ float c_s[64];           // persistent cell state (blocks < 64)
  __shared__ float sm[4], sden[4], snum[4][256];

  // constant tail of out: [zeros(1536) | arange(512) | zeros(512)] — no dependencies
  if (blk >= 100 && blk < 110) {
    int idx = 8192 + (blk - 100) * 256 + t;
    out[idx] = (idx >= 9728 && idx < 10240) ? (float)(idx - 9728) : 0.0f;
  }
  if (blk < 64 && t < 64) c_s[t] = 0.0f;

  const int s_at = blk >> 5, j_at = blk & (CPS - 1);
  const int lo = segb[s_at], hi = segb[s_at + 1];
  const float4* h4 = (const float4*)h;

  for (int step = 0; step < 8; ++step) {
    // ---- P_work: blocks (s,q) = (blk>>2, blk&3): merge r(step-1) + LSTM -> h(step) ----
    if (blk < 64) {
      const int s = blk >> 2, q = blk & 3;
      if (step == 0) {
        Xl[t] = 0.f; Xl[256 + t] = 0.f; Xl[512 + t] = 0.f;
      } else {
        float hv = hl_g[s * 256 + t];
        float M = -INFINITY;
#pragma unroll
        for (int j = 0; j < CPS; ++j) M = fmaxf(M, pm[s * CPS + j]);
        float den = 0.f, num = 0.f;
#pragma unroll 4
        for (int j = 0; j < CPS; ++j) {
          float mj = pm[s * CPS + j];
          float w = (mj == -INFINITY) ? 0.f : __expf(mj - M);
          den += w * pden[s * CPS + j];
          num += w * pnum[(size_t)(s * CPS + j) * 256 + t];
        }
        float r = (den > 0.f) ? num / den : 0.f;
        Xl[t] = hv; Xl[256 + t] = r; Xl[512 + t] = hv;
      }
      __syncthreads();
      const int g = (t >> 6) * 256 + q * 64 + (t & 63);
      float acc = bias[g];
#pragma unroll 8
      for (int k = 0; k < 768; ++k) acc += Xl[k] * wT[(size_t)k * 1024 + g];
      gl[(t >> 6) * 64 + (t & 63)] = acc;
      __syncthreads();
      if (t < 64) {
        float ig = gl[t], fg = gl[64 + t], gg = gl[128 + t], og = gl[192 + t];
        float cv = sigm(fg) * c_s[t] + sigm(ig) * tanhf(gg);
        float hv = sigm(og) * tanhf(cv);
        c_s[t] = cv;
        hl_g[s * 256 + q * 64 + t] = hv;
      }
    }
    gridbar(&bars[2 * step]);
    // ---- P_attn: all 512 blocks, online softmax over contiguous chunk ----
    {
      int cnt = hi - lo;
      int chunk = (cnt + CPS - 1) >> 5;
      int blo = lo + j_at * chunk;
      int bhi = min(blo + chunk, hi);
      int wv = t >> 6, lane = t & 63;
      float4 qv = ((const float4*)hl_g)[s_at * 64 + lane];
      float m = -INFINITY, den = 0.f;
      float ax = 0.f, ay = 0.f, az = 0.f, aw = 0.f;
      int n = blo + wv;
      for (; n + 4 < bhi; n += 8) {
        float4 h1 = h4[(size_t)n * 64 + lane];
        float4 h2 = h4[(size_t)(n + 4) * 64 + lane];
        float e1 = h1.x * qv.x + h1.y * qv.y + h1.z * qv.z + h1.w * qv.w;
        float e2 = h2.x * qv.x + h2.y * qv.y + h2.z * qv.z + h2.w * qv.w;
#pragma unroll
        for (int off = 32; off; off >>= 1) { e1 += __shfl_xor(e1, off); e2 += __shfl_xor(e2, off); }
        float mn = fmaxf(m, fmaxf(e1, e2));
        float scl = __expf(m - mn);
        float p1 = __expf(e1 - mn), p2 = __expf(e2 - mn);
        den = den * scl + p1 + p2;
        ax = ax * scl + p1 * h1.x + p2 * h2.x;
        ay = ay * scl + p1 * h1.y + p2 * h2.y;
        az = az * scl + p1 * h1.z + p2 * h2.z;
        aw = aw * scl + p1 * h1.w + p2 * h2.w;
        m = mn;
      }
      for (; n < bhi; n += 4) {
        float4 h1 = h4[(size_t)n * 64 + lane];
        float e1 = h1.x * qv.x + h1.y * qv.y + h1.z * qv.z + h1.w * qv.w;
#pragma unroll
        for (int off = 32; off; off >>= 1) e1 += __shfl_xor(e1, off);
        float mn = fmaxf(m, e1);
        float scl = __expf(m - mn);
        float p1 = __expf(e1 - mn);
        den = den * scl + p1;
        ax = ax * scl + p1 * h1.x;
        ay = ay * scl + p1 * h1.y;
        az = az * scl + p1 * h1.z;
        aw = aw * scl + p1 * h1.w;
        m = mn;
      }
      if (lane == 0) { sm[wv] = m; sden[wv] = den; }
      ((float4*)snum[wv])[lane] = make_float4(ax, ay, az, aw);
      __syncthreads();
      float M = fmaxf(fmaxf(sm[0], sm[1]), fmaxf(sm[2], sm[3]));
      float D = 0.f, nm = 0.f;
      if (M > -INFINITY) {
#pragma unroll
        for (int wq = 0; wq < 4; ++wq) {
          float wgt = (sm[wq] == -INFINITY) ? 0.f : __expf(sm[wq] - M);
          D += wgt * sden[wq];
          nm += wgt * snum[wq][t];
        }
      }
      if (t == 0) { pm[blk] = M; pden[blk] = D; }
      pnum[(size_t)blk * 256 + t] = nm;
    }
    gridbar(&bars[2 * step + 1]);
  }
  // ---- final: q_star(7) = [h(7), r(7)] -> out[0:8192] ----
  if (blk < 16) {
    float hv = hl_g[blk * 256 + t];
    float M = -INFINITY;
#pragma unroll
    for (int j = 0; j < CPS; ++j) M = fmaxf(M, pm[blk * CPS + j]);
    float den = 0.f, num = 0.f;
#pragma unroll 4
    for (int j = 0; j < CPS; ++j) {
      float mj = pm[blk * CPS + j];
      float w = (mj == -INFINITY) ? 0.f : __expf(mj - M);
      den += w * pden[blk * CPS + j];
      num += w * pnum[(size_t)(blk * CPS + j) * 256 + t];
    }
    float r = (den > 0.f) ? num / den : 0.f;
    out[blk * 512 + t] = hv;
    out[blk * 512 + 256 + t] = r;
  }
}

extern "C" void kernel_launch(void* const* d_in, const int* in_sizes, int n_in,
                              void* d_out, int out_size, void* d_ws, size_t ws_size,
                              hipStream_t stream) {
  const float* x    = (const float*)d_in[0];
  const int*   batch= (const int*)d_in[3];
  const float* bw0  = (const float*)d_in[4];
  const float* sw0  = (const float*)d_in[5];
  const float* sc0  = (const float*)d_in[6];
  const float* bw1  = (const float*)d_in[7];
  const float* sw1  = (const float*)d_in[8];
  const float* sc1  = (const float*)d_in[9];
  const float* ln_g = (const float*)d_in[10];
  const float* ln_b = (const float*)d_in[11];
  const float* w_ih = (const float*)d_in[12];
  const float* w_hh = (const float*)d_in[13];
  const float* b_ih = (const float*)d_in[14];
  const float* b_hh = (const float*)d_in[15];
  float* ws = (float*)d_ws;
  const bool split = ws_size >= SPLIT_NEED_F * 4ull;  // constant per session -> graph-safe

  prep_kernel<<<7077, 256, 0, stream>>>(bw0, sw0, sc0, bw1, sw1, sc1, w_ih, w_hh,
                                        b_ih, b_hh, batch, ws);
  if (split) {
    short* Af = (short*)(ws + AF_OFF);
    expand_kernel<64><<<2048, 256, 0, stream>>>(x, Af);
    gemm_mfma<576, 128><<<dim3(512, 1), 256, 0, stream>>>(Af, (const short*)(ws + WD0_OFF), ws + H1_OFF);
    expand_kernel<128><<<2048, 256, 0, stream>>>(ws + H1_OFF, Af);
    gemm_mfma<1152, 256><<<dim3(512, 2), 256, 0, stream>>>(Af, (const short*)(ws + WD1_OFF), ws + H2_OFF);
  } else {
    kan_mfma<64, 128><<<dim3(512, 1), 256, 0, stream>>>(x, (const short*)(ws + WB0_OFF), ws + H1_OFF);
    kan_mfma<128, 256><<<dim3(512, 2), 256, 0, stream>>>(ws + H1_OFF, (const short*)(ws + WB1_OFF), ws + H2_OFF);
  }
  ln_kernel<<<16384, 256, 0, stream>>>(ws + H2_OFF, ln_g, ln_b);
  set2set_coop<<<CBLK, 256, 0, stream>>>(ws + H2_OFF, (const int*)(ws + SEGB_OFF),
                                         ws + WTIH_OFF, ws + BIAS_OFF,
                                         ws + HLG_OFF, ws + PM_OFF, ws + PDEN_OFF,
                                         ws + PNUM_OFF, (int*)(ws + BARS_OFF),
                                         (float*)d_out);
}

// Round 8
// 694.021 us; speedup vs baseline: 3.7693x; 3.7693x over previous
//
#include <hip/hip_runtime.h>
#include <math.h>

#define N_NODES 65536
#define NB 16
#define BPS 32   // chunks (blocks) per segment in attn

// ---- ws layout (float offsets) ----
#define WD0_OFF   0ull          // dense W0: 128*576 bf16 = 36864 f
#define WD1_OFF   36864ull      // dense W1: 256*1152 bf16 = 147456 f
#define WTIH_OFF  184320ull     // 512*1024 f (wT rows 0..511)
#define WTHH_OFF  708608ull     // 256*1024 f (wT rows 512..767, contiguous after WTIH)
#define BIAS_OFF  970752ull     // 1024 f
#define C_OFF     971776ull     // 16*256 f
#define HL_OFF    975872ull     // 16*256 f
#define SEGB_OFF  979968ull     // 17 ints (+pad)
#define PM_OFF    980000ull     // 512 f
#define PDEN_OFF  980512ull     // 512 f
#define PNUM_OFF  981024ull     // 512*256 f = 131072
#define H1_OFF    1112096ull    // N*128 f
#define H2_OFF    9500704ull    // N*256 f
#define AF_OFF    26277920ull   // 65536*1152 bf16 = 37748736 f
#define H2B_OFF   26277920ull   // N*256 bf16 = 16777216 f  (aliases AF; AF dead after gemm1)
#define SPLIT_NEED_F 64026656ull

typedef __attribute__((ext_vector_type(8))) short s16x8;
typedef __attribute__((ext_vector_type(4))) float f32x4;

__device__ __forceinline__ float sigm(float x) {
  return __builtin_amdgcn_rcpf(1.0f + __expf(-x));
}

__device__ __forceinline__ short f2bf(float f) {
  union { float f; unsigned u; } v; v.f = f;
  unsigned r = (v.u + 0x7FFFu + ((v.u >> 16) & 1u)) >> 16;
  return (short)r;
}

__device__ __forceinline__ float bf2f(unsigned short u) {
  return __uint_as_float(((unsigned)u) << 16);
}

__device__ __forceinline__ void bspline_bases(float x, float b8[8]) {
  float t[12];
#pragma unroll
  for (int i = 0; i < 12; ++i) t[i] = (float)(i - 3) * 0.4f - 1.0f;
  float b[11];
#pragma unroll
  for (int i = 0; i < 11; ++i) b[i] = (x >= t[i] && x < t[i + 1]) ? 1.0f : 0.0f;
#pragma unroll
  for (int k = 1; k <= 3; ++k) {
#pragma unroll
    for (int i = 0; i + k < 11; ++i) {
      float invl = 1.0f / (t[i + k] - t[i]);
      float invr = 1.0f / (t[i + k + 1] - t[i + 1]);
      b[i] = (x - t[i]) * invl * b[i] + (t[i + k + 1] - x) * invr * b[i + 1];
    }
  }
#pragma unroll
  for (int j = 0; j < 8; ++j) b8[j] = b[j];
}

// ---- prep: dense bf16 KAN weights, LSTM wT (f32), bias, zero c/hl, segb ----
__global__ __launch_bounds__(256) void prep_kernel(
    const float* __restrict__ bw0, const float* __restrict__ sw0, const float* __restrict__ sc0,
    const float* __restrict__ bw1, const float* __restrict__ sw1, const float* __restrict__ sc1,
    const float* __restrict__ w_ih, const float* __restrict__ w_hh,
    const float* __restrict__ b_ih, const float* __restrict__ b_hh,
    const int* __restrict__ batch,
    float* __restrict__ ws) {
  int id = blockIdx.x * 256 + threadIdx.x;
  if (id < 73728) {                        // Wd0 dense: [128][576]
    int o = id / 576, k = id % 576;
    float v;
    if (k < 64) v = bw0[o * 64 + k];
    else { int kk = k - 64, d = kk >> 3, j = kk & 7;
           v = sw0[(o * 64 + d) * 8 + j] * sc0[o * 64 + d]; }
    ((short*)(ws + WD0_OFF))[id] = f2bf(v);
  } else if (id < 368640) {                // Wd1 dense: [256][1152]
    int l = id - 73728;
    int o = l / 1152, k = l % 1152;
    float v;
    if (k < 128) v = bw1[o * 128 + k];
    else { int kk = k - 128, d = kk >> 3, j = kk & 7;
           v = sw1[(o * 128 + d) * 8 + j] * sc1[o * 128 + d]; }
    ((short*)(ws + WD1_OFF))[l] = f2bf(v);
  } else if (id < 892928) {                // wT_ih: [512][1024]
    int l = id - 368640; int k = l >> 10, g = l & 1023;
    ws[WTIH_OFF + l] = w_ih[g * 512 + k];
  } else if (id < 1155072) {               // wT_hh: [256][1024]
    int l = id - 892928; int k = l >> 10, g = l & 1023;
    ws[WTHH_OFF + l] = w_hh[g * 256 + k];
  } else if (id < 1156096) {
    int g = id - 1155072;
    ws[BIAS_OFF + g] = b_ih[g] + b_hh[g];
  } else if (id < 1164288) {
    ws[C_OFF + (id - 1156096)] = 0.0f;     // c, hl contiguous (8192 f)
  } else if (id < 1164305) {
    int s = id - 1164288;
    int lo = 0, hi = N_NODES;
    while (lo < hi) { int mid = (lo + hi) >> 1; if (batch[mid] < s) lo = mid + 1; else hi = mid; }
    ((int*)(ws + SEGB_OFF))[s] = lo;
  }
}

// ---- expansion: x[N][IN] f32 -> Af[N][9*IN] bf16 dense ----
template <int IN>
__global__ __launch_bounds__(256) void expand_kernel(const float* __restrict__ in,
                                                     short* __restrict__ Af) {
  constexpr int RS = 9 * IN;
  const int total = N_NODES * IN;
  for (int id = blockIdx.x * 256 + threadIdx.x; id < total; id += gridDim.x * 256) {
    int n = id / IN;
    int d = id & (IN - 1);
    float v = in[id];
    float sv = v * sigm(v);
    float b8[8];
    bspline_bases(v, b8);
    short* rowp = Af + (size_t)n * RS;
    rowp[d] = f2bf(sv);
    s16x8 q;
#pragma unroll
    for (int j = 0; j < 8; ++j) q[j] = f2bf(b8[j]);
    ((s16x8*)(rowp + IN))[d] = q;
  }
}

// ---- pure GEMM: out[N][OUT] = A[N][K]bf16 @ W[OUT][K]bf16^T. BK=96, 128x128 tile ----
template <int K, int OUT>
__global__ __launch_bounds__(256, 2) void gemm_mfma(const short* __restrict__ A,
                                                    const short* __restrict__ Wp,
                                                    float* __restrict__ out) {
  constexpr int CHUNKS = K / 96;
  __shared__ s16x8 As[1536];
  __shared__ s16x8 Bs[1536];
  const int tid = threadIdx.x;
  const int n0 = blockIdx.x * 128;
  const int nb0 = blockIdx.y * 128;
  const int lane = tid & 63;
  const int wid = tid >> 6;
  const int wr = wid >> 1, wc = wid & 1;
  const int l15 = lane & 15, l4 = lane >> 4;

  f32x4 acc[4][4] = {};

  for (int c = 0; c < CHUNKS; ++c) {
    if (c) __syncthreads();
    const short* abase = A + (size_t)n0 * K + c * 96;
    const short* bbase = Wp + (size_t)nb0 * K + c * 96;
#pragma unroll
    for (int i = 0; i < 6; ++i) {
      int s = i * 256 + tid;
      int kg = s >> 7, row = s & 127;
      __builtin_amdgcn_global_load_lds(
          (const __attribute__((address_space(1))) unsigned int*)(abase + (size_t)row * K + kg * 8),
          (__attribute__((address_space(3))) unsigned int*)&As[s], 16, 0, 0);
      __builtin_amdgcn_global_load_lds(
          (const __attribute__((address_space(1))) unsigned int*)(bbase + (size_t)row * K + kg * 8),
          (__attribute__((address_space(3))) unsigned int*)&Bs[s], 16, 0, 0);
    }
    __syncthreads();
#pragma unroll
    for (int kk = 0; kk < 3; ++kk) {
      s16x8 a[4], b[4];
#pragma unroll
      for (int mi = 0; mi < 4; ++mi)
        a[mi] = As[(kk * 4 + l4) * 128 + wr * 64 + mi * 16 + l15];
#pragma unroll
      for (int ni = 0; ni < 4; ++ni)
        b[ni] = Bs[(kk * 4 + l4) * 128 + wc * 64 + ni * 16 + l15];
#pragma unroll
      for (int mi = 0; mi < 4; ++mi)
#pragma unroll
        for (int ni = 0; ni < 4; ++ni)
          acc[mi][ni] = __builtin_amdgcn_mfma_f32_16x16x32_bf16(a[mi], b[ni], acc[mi][ni], 0, 0, 0);
    }
  }
#pragma unroll
  for (int mi = 0; mi < 4; ++mi) {
#pragma unroll
    for (int r = 0; r < 4; ++r) {
      int m = wr * 64 + mi * 16 + l4 * 4 + r;
      float* orow = out + (size_t)(n0 + m) * OUT + nb0;
#pragma unroll
      for (int ni = 0; ni < 4; ++ni)
        orow[wc * 64 + ni * 16 + l15] = acc[mi][ni][r];
    }
  }
}

// ---- LayerNorm over 256 dims, one wave per node; f32 in -> bf16 out ----
__global__ __launch_bounds__(256) void ln_kernel(const float* __restrict__ h,
                                                 const float* __restrict__ g,
                                                 const float* __restrict__ b,
                                                 short* __restrict__ hb) {
  int gid = blockIdx.x * 256 + threadIdx.x;
  int node = gid >> 6;
  int lane = gid & 63;
  const float4* row = (const float4*)(h + (size_t)node * 256);
  float4 v = row[lane];
  float s1 = v.x + v.y + v.z + v.w;
  float s2 = v.x * v.x + v.y * v.y + v.z * v.z + v.w * v.w;
#pragma unroll
  for (int off = 32; off; off >>= 1) { s1 += __shfl_xor(s1, off); s2 += __shfl_xor(s2, off); }
  float mu = s1 * (1.0f / 256.0f);
  float var = s2 * (1.0f / 256.0f) - mu * mu;
  float rs = rsqrtf(var + 1e-5f);
  float4 g4 = ((const float4*)g)[lane];
  float4 b4 = ((const float4*)b)[lane];
  short4 o;
  o.x = f2bf((v.x - mu) * rs * g4.x + b4.x);
  o.y = f2bf((v.y - mu) * rs * g4.y + b4.y);
  o.z = f2bf((v.z - mu) * rs * g4.z + b4.z);
  o.w = f2bf((v.w - mu) * rs * g4.w + b4.w);
  *(short4*)(hb + (size_t)node * 256 + lane * 4) = o;
}

// ---- fused merge(prev step) + LSTM: 64 blocks, block (s,q) ----
__global__ __launch_bounds__(256) void lstm_merge(const float* __restrict__ wT,
                                                  const float* __restrict__ bias,
                                                  float* __restrict__ c,
                                                  float* __restrict__ hl,
                                                  const float* __restrict__ pm,
                                                  const float* __restrict__ pden,
                                                  const float* __restrict__ pnum,
                                                  int step) {
  int blk = blockIdx.x;
  int s = blk >> 2, q = blk & 3;
  int t = threadIdx.x;
  __shared__ float Xl[768], gl[256];
  if (step == 0) {
    Xl[t] = 0.f; Xl[256 + t] = 0.f; Xl[512 + t] = 0.f;
  } else {
    float hv = hl[s * 256 + t];
    float M = -INFINITY;
#pragma unroll
    for (int j = 0; j < BPS; ++j) M = fmaxf(M, pm[s * BPS + j]);
    float den = 0.f, num = 0.f;
#pragma unroll 4
    for (int j = 0; j < BPS; ++j) {
      float mj = pm[s * BPS + j];
      float w = (mj == -INFINITY) ? 0.f : __expf(mj - M);
      den += w * pden[s * BPS + j];
      num += w * pnum[(size_t)(s * BPS + j) * 256 + t];
    }
    float r = (den > 0.f) ? num / den : 0.f;
    Xl[t] = hv; Xl[256 + t] = r; Xl[512 + t] = hv;
  }
  __syncthreads();
  const int g = (t >> 6) * 256 + q * 64 + (t & 63);
  float acc = bias[g];
#pragma unroll 8
  for (int k = 0; k < 768; ++k) acc += Xl[k] * wT[(size_t)k * 1024 + g];
  gl[(t >> 6) * 64 + (t & 63)] = acc;
  __syncthreads();
  if (t < 64) {
    int cl = q * 64 + t;
    float ig = gl[t], fg = gl[64 + t], gg = gl[128 + t], og = gl[192 + t];
    float cv = sigm(fg) * c[s * 256 + cl] + sigm(ig) * tanhf(gg);
    float hv = sigm(og) * tanhf(cv);
    c[s * 256 + cl] = cv;
    hl[s * 256 + cl] = hv;
  }
}

// ---- attn: 512 blocks (16 seg x 32 chunks). 16-lane group per node; bf16 h.
//      Each group: online softmax over its node stream; 16-group LDS combine. ----
__global__ __launch_bounds__(256) void attn_kernel(const short* __restrict__ hb,
                                                   const float* __restrict__ hl,
                                                   const int* __restrict__ segb,
                                                   float* __restrict__ pm,
                                                   float* __restrict__ pden,
                                                   float* __restrict__ pnum) {
  int blk = blockIdx.x;
  int s = blk >> 5, j = blk & (BPS - 1);
  int lo = segb[s], hi = segb[s + 1];
  int cnt = hi - lo;
  int chunk = (cnt + BPS - 1) >> 5;
  int blo = lo + j * chunk;
  int bhi = min(blo + chunk, hi);
  int t = threadIdx.x;
  int gid = t >> 4, sl = t & 15;
  // q slice: 16 f32 per lane
  float qr[16];
  const float4* q4 = (const float4*)(hl + s * 256 + sl * 16);
#pragma unroll
  for (int i = 0; i < 4; ++i) {
    float4 v = q4[i];
    qr[4 * i] = v.x; qr[4 * i + 1] = v.y; qr[4 * i + 2] = v.z; qr[4 * i + 3] = v.w;
  }
  float m = -INFINITY, den = 0.f;
  float acc[16] = {};
  for (int n = blo + gid; n < bhi; n += 16) {
    const s16x8* hp = (const s16x8*)(hb + (size_t)n * 256 + sl * 16);
    s16x8 u0 = hp[0], u1 = hp[1];
    float hv[16];
#pragma unroll
    for (int k = 0; k < 8; ++k) hv[k] = bf2f((unsigned short)u0[k]);
#pragma unroll
    for (int k = 0; k < 8; ++k) hv[8 + k] = bf2f((unsigned short)u1[k]);
    float d0 = 0.f, d1 = 0.f;
#pragma unroll
    for (int k = 0; k < 8; ++k) {
      d0 = fmaf(hv[k], qr[k], d0);
      d1 = fmaf(hv[8 + k], qr[8 + k], d1);
    }
    float e = d0 + d1;
    e += __shfl_xor(e, 1); e += __shfl_xor(e, 2);
    e += __shfl_xor(e, 4); e += __shfl_xor(e, 8);
    float mn = fmaxf(m, e);
    float scl = __expf(m - mn);
    float p = __expf(e - mn);
    den = den * scl + p;
#pragma unroll
    for (int k = 0; k < 16; ++k) acc[k] = acc[k] * scl + p * hv[k];
    m = mn;
  }
  __shared__ float sm[16], sden[16], racc[16][256];
  if (sl == 0) { sm[gid] = m; sden[gid] = den; }
#pragma unroll
  for (int i = 0; i < 4; ++i)
    ((float4*)&racc[gid][sl * 16])[i] = make_float4(acc[4 * i], acc[4 * i + 1], acc[4 * i + 2], acc[4 * i + 3]);
  __syncthreads();
  float M = -INFINITY;
#pragma unroll
  for (int g = 0; g < 16; ++g) M = fmaxf(M, sm[g]);
  float D = 0.f, nm = 0.f;
  if (M > -INFINITY) {
#pragma unroll
    for (int g = 0; g < 16; ++g) {
      float w = (sm[g] == -INFINITY) ? 0.f : __expf(sm[g] - M);
      D += w * sden[g];
      nm += w * racc[g][t];
    }
  }
  if (t == 0) { pm[blk] = M; pden[blk] = D; }
  pnum[(size_t)blk * 256 + t] = nm;
}

// ---- final: blocks 0-15 merge last attn + write [q,r]; blocks 16-25 write tail ----
__global__ __launch_bounds__(256) void final_kernel(const float* __restrict__ pm,
                                                    const float* __restrict__ pden,
                                                    const float* __restrict__ pnum,
                                                    const float* __restrict__ hl,
                                                    float* __restrict__ out) {
  int blk = blockIdx.x, t = threadIdx.x;
  if (blk < 16) {
    float hv = hl[blk * 256 + t];
    float M = -INFINITY;
#pragma unroll
    for (int j = 0; j < BPS; ++j) M = fmaxf(M, pm[blk * BPS + j]);
    float den = 0.f, num = 0.f;
#pragma unroll 4
    for (int j = 0; j < BPS; ++j) {
      float mj = pm[blk * BPS + j];
      float w = (mj == -INFINITY) ? 0.f : __expf(mj - M);
      den += w * pden[blk * BPS + j];
      num += w * pnum[(size_t)(blk * BPS + j) * 256 + t];
    }
    float r = (den > 0.f) ? num / den : 0.f;
    out[blk * 512 + t] = hv;
    out[blk * 512 + 256 + t] = r;
  } else {
    int idx = 8192 + (blk - 16) * 256 + t;   // 2560 tail elems
    out[idx] = (idx >= 9728 && idx < 10240) ? (float)(idx - 9728) : 0.0f;
  }
}

extern "C" void kernel_launch(void* const* d_in, const int* in_sizes, int n_in,
                              void* d_out, int out_size, void* d_ws, size_t ws_size,
                              hipStream_t stream) {
  const float* x    = (const float*)d_in[0];
  const int*   batch= (const int*)d_in[3];
  const float* bw0  = (const float*)d_in[4];
  const float* sw0  = (const float*)d_in[5];
  const float* sc0  = (const float*)d_in[6];
  const float* bw1  = (const float*)d_in[7];
  const float* sw1  = (const float*)d_in[8];
  const float* sc1  = (const float*)d_in[9];
  const float* ln_g = (const float*)d_in[10];
  const float* ln_b = (const float*)d_in[11];
  const float* w_ih = (const float*)d_in[12];
  const float* w_hh = (const float*)d_in[13];
  const float* b_ih = (const float*)d_in[14];
  const float* b_hh = (const float*)d_in[15];
  float* ws = (float*)d_ws;

  prep_kernel<<<4549, 256, 0, stream>>>(bw0, sw0, sc0, bw1, sw1, sc1, w_ih, w_hh,
                                        b_ih, b_hh, batch, ws);
  short* Af = (short*)(ws + AF_OFF);
  expand_kernel<64><<<2048, 256, 0, stream>>>(x, Af);
  gemm_mfma<576, 128><<<dim3(512, 1), 256, 0, stream>>>(Af, (const short*)(ws + WD0_OFF), ws + H1_OFF);
  expand_kernel<128><<<2048, 256, 0, stream>>>(ws + H1_OFF, Af);
  gemm_mfma<1152, 256><<<dim3(512, 2), 256, 0, stream>>>(Af, (const short*)(ws + WD1_OFF), ws + H2_OFF);
  ln_kernel<<<16384, 256, 0, stream>>>(ws + H2_OFF, ln_g, ln_b, (short*)(ws + H2B_OFF));
  const int* segb = (const int*)(ws + SEGB_OFF);
  for (int step = 0; step < 8; ++step) {
    lstm_merge<<<64, 256, 0, stream>>>(ws + WTIH_OFF, ws + BIAS_OFF, ws + C_OFF, ws + HL_OFF,
                                       ws + PM_OFF, ws + PDEN_OFF, ws + PNUM_OFF, step);
    attn_kernel<<<NB * BPS, 256, 0, stream>>>((const short*)(ws + H2B_OFF), ws + HL_OFF, segb,
                                              ws + PM_OFF, ws + PDEN_OFF, ws + PNUM_OFF);
  }
  final_kernel<<<26, 256, 0, stream>>>(ws + PM_OFF, ws + PDEN_OFF, ws + PNUM_OFF,
                                       ws + HL_OFF, (float*)d_out);
}

// Round 9
// 498.396 us; speedup vs baseline: 5.2487x; 1.3925x over previous
//
#include <hip/hip_runtime.h>
#include <math.h>

#define N_NODES 65536
#define NB 16
#define BPS 32   // chunks (blocks) per segment in attn

// ---- ws layout (float offsets) ----
#define WD0_OFF   0ull          // dense W0: 128*576 bf16 = 36864 f
#define WD1_OFF   36864ull      // dense W1: 256*1152 bf16 = 147456 f
#define WTIH_OFF  184320ull     // 512*1024 f (wT rows 0..511)
#define WTHH_OFF  708608ull     // 256*1024 f (wT rows 512..767, contiguous after WTIH)
#define BIAS_OFF  970752ull     // 1024 f
#define C_OFF     971776ull     // 16*256 f
#define HL_OFF    975872ull     // 16*256 f
#define SEGB_OFF  979968ull     // 17 ints (+pad)
#define PM_OFF    980000ull     // 512 f
#define PDEN_OFF  980512ull     // 512 f
#define PNUM_OFF  981024ull     // 512*256 f = 131072
#define H1_OFF    1112096ull    // N*128 f
#define H2_OFF    9500704ull    // N*256 f
#define AF_OFF    26277920ull   // 65536*1152 bf16 = 37748736 f
#define H2B_OFF   26277920ull   // N*256 bf16 (aliases AF; AF dead after gemm1)

typedef __attribute__((ext_vector_type(8))) short s16x8;
typedef __attribute__((ext_vector_type(4))) float f32x4;

__device__ __forceinline__ float sigm(float x) {
  return __builtin_amdgcn_rcpf(1.0f + __expf(-x));
}

__device__ __forceinline__ short f2bf(float f) {
  union { float f; unsigned u; } v; v.f = f;
  unsigned r = (v.u + 0x7FFFu + ((v.u >> 16) & 1u)) >> 16;
  return (short)r;
}

__device__ __forceinline__ float bf2f(unsigned short u) {
  return __uint_as_float(((unsigned)u) << 16);
}

__device__ __forceinline__ void bspline_bases(float x, float b8[8]) {
  float t[12];
#pragma unroll
  for (int i = 0; i < 12; ++i) t[i] = (float)(i - 3) * 0.4f - 1.0f;
  float b[11];
#pragma unroll
  for (int i = 0; i < 11; ++i) b[i] = (x >= t[i] && x < t[i + 1]) ? 1.0f : 0.0f;
#pragma unroll
  for (int k = 1; k <= 3; ++k) {
#pragma unroll
    for (int i = 0; i + k < 11; ++i) {
      float invl = 1.0f / (t[i + k] - t[i]);
      float invr = 1.0f / (t[i + k + 1] - t[i + 1]);
      b[i] = (x - t[i]) * invl * b[i] + (t[i + k + 1] - x) * invr * b[i + 1];
    }
  }
#pragma unroll
  for (int j = 0; j < 8; ++j) b8[j] = b[j];
}

// ---- prep: dense bf16 KAN weights, LSTM wT (f32), bias, zero c/hl, segb ----
__global__ __launch_bounds__(256) void prep_kernel(
    const float* __restrict__ bw0, const float* __restrict__ sw0, const float* __restrict__ sc0,
    const float* __restrict__ bw1, const float* __restrict__ sw1, const float* __restrict__ sc1,
    const float* __restrict__ w_ih, const float* __restrict__ w_hh,
    const float* __restrict__ b_ih, const float* __restrict__ b_hh,
    const int* __restrict__ batch,
    float* __restrict__ ws) {
  int id = blockIdx.x * 256 + threadIdx.x;
  if (id < 73728) {                        // Wd0 dense: [128][576]
    int o = id / 576, k = id % 576;
    float v;
    if (k < 64) v = bw0[o * 64 + k];
    else { int kk = k - 64, d = kk >> 3, j = kk & 7;
           v = sw0[(o * 64 + d) * 8 + j] * sc0[o * 64 + d]; }
    ((short*)(ws + WD0_OFF))[id] = f2bf(v);
  } else if (id < 368640) {                // Wd1 dense: [256][1152]
    int l = id - 73728;
    int o = l / 1152, k = l % 1152;
    float v;
    if (k < 128) v = bw1[o * 128 + k];
    else { int kk = k - 128, d = kk >> 3, j = kk & 7;
           v = sw1[(o * 128 + d) * 8 + j] * sc1[o * 128 + d]; }
    ((short*)(ws + WD1_OFF))[l] = f2bf(v);
  } else if (id < 892928) {                // wT_ih: [512][1024]
    int l = id - 368640; int k = l >> 10, g = l & 1023;
    ws[WTIH_OFF + l] = w_ih[g * 512 + k];
  } else if (id < 1155072) {               // wT_hh: [256][1024]
    int l = id - 892928; int k = l >> 10, g = l & 1023;
    ws[WTHH_OFF + l] = w_hh[g * 256 + k];
  } else if (id < 1156096) {
    int g = id - 1155072;
    ws[BIAS_OFF + g] = b_ih[g] + b_hh[g];
  } else if (id < 1164288) {
    ws[C_OFF + (id - 1156096)] = 0.0f;     // c, hl contiguous (8192 f)
  } else if (id < 1164305) {
    int s = id - 1164288;
    int lo = 0, hi = N_NODES;
    while (lo < hi) { int mid = (lo + hi) >> 1; if (batch[mid] < s) lo = mid + 1; else hi = mid; }
    ((int*)(ws + SEGB_OFF))[s] = lo;
  }
}

// ---- expansion: x[N][IN] f32 -> Af[N][9*IN] bf16 dense ----
template <int IN>
__global__ __launch_bounds__(256) void expand_kernel(const float* __restrict__ in,
                                                     short* __restrict__ Af) {
  constexpr int RS = 9 * IN;
  const int total = N_NODES * IN;
  for (int id = blockIdx.x * 256 + threadIdx.x; id < total; id += gridDim.x * 256) {
    int n = id / IN;
    int d = id & (IN - 1);
    float v = in[id];
    float sv = v * sigm(v);
    float b8[8];
    bspline_bases(v, b8);
    short* rowp = Af + (size_t)n * RS;
    rowp[d] = f2bf(sv);
    s16x8 q;
#pragma unroll
    for (int j = 0; j < 8; ++j) q[j] = f2bf(b8[j]);
    ((s16x8*)(rowp + IN))[d] = q;
  }
}

// ---- pure GEMM: out[N][OUT] = A[N][K]bf16 @ W[OUT][K]bf16^T. BK=96, 128x128 tile.
//      3 blocks/CU (48KB LDS x3 = 144 <= 160KB): cross-block overlap hides barrier drain. ----
template <int K, int OUT>
__global__ __launch_bounds__(256, 3) void gemm_mfma(const short* __restrict__ A,
                                                    const short* __restrict__ Wp,
                                                    float* __restrict__ out) {
  constexpr int CHUNKS = K / 96;
  __shared__ s16x8 As[1536];
  __shared__ s16x8 Bs[1536];
  const int tid = threadIdx.x;
  const int n0 = blockIdx.x * 128;
  const int nb0 = blockIdx.y * 128;
  const int lane = tid & 63;
  const int wid = tid >> 6;
  const int wr = wid >> 1, wc = wid & 1;
  const int l15 = lane & 15, l4 = lane >> 4;

  f32x4 acc[4][4] = {};

  for (int c = 0; c < CHUNKS; ++c) {
    if (c) __syncthreads();
    const short* abase = A + (size_t)n0 * K + c * 96;
    const short* bbase = Wp + (size_t)nb0 * K + c * 96;
#pragma unroll
    for (int i = 0; i < 6; ++i) {
      int s = i * 256 + tid;
      int kg = s >> 7, row = s & 127;
      __builtin_amdgcn_global_load_lds(
          (const __attribute__((address_space(1))) unsigned int*)(abase + (size_t)row * K + kg * 8),
          (__attribute__((address_space(3))) unsigned int*)&As[s], 16, 0, 0);
      __builtin_amdgcn_global_load_lds(
          (const __attribute__((address_space(1))) unsigned int*)(bbase + (size_t)row * K + kg * 8),
          (__attribute__((address_space(3))) unsigned int*)&Bs[s], 16, 0, 0);
    }
    __syncthreads();
#pragma unroll
    for (int kk = 0; kk < 3; ++kk) {
      s16x8 a[4], b[4];
#pragma unroll
      for (int mi = 0; mi < 4; ++mi)
        a[mi] = As[(kk * 4 + l4) * 128 + wr * 64 + mi * 16 + l15];
#pragma unroll
      for (int ni = 0; ni < 4; ++ni)
        b[ni] = Bs[(kk * 4 + l4) * 128 + wc * 64 + ni * 16 + l15];
#pragma unroll
      for (int mi = 0; mi < 4; ++mi)
#pragma unroll
        for (int ni = 0; ni < 4; ++ni)
          acc[mi][ni] = __builtin_amdgcn_mfma_f32_16x16x32_bf16(a[mi], b[ni], acc[mi][ni], 0, 0, 0);
    }
  }
#pragma unroll
  for (int mi = 0; mi < 4; ++mi) {
#pragma unroll
    for (int r = 0; r < 4; ++r) {
      int m = wr * 64 + mi * 16 + l4 * 4 + r;
      float* orow = out + (size_t)(n0 + m) * OUT + nb0;
#pragma unroll
      for (int ni = 0; ni < 4; ++ni)
        orow[wc * 64 + ni * 16 + l15] = acc[mi][ni][r];
    }
  }
}

// ---- LayerNorm over 256 dims, one wave per node; f32 in -> bf16 out ----
__global__ __launch_bounds__(256) void ln_kernel(const float* __restrict__ h,
                                                 const float* __restrict__ g,
                                                 const float* __restrict__ b,
                                                 short* __restrict__ hb) {
  int gid = blockIdx.x * 256 + threadIdx.x;
  int node = gid >> 6;
  int lane = gid & 63;
  const float4* row = (const float4*)(h + (size_t)node * 256);
  float4 v = row[lane];
  float s1 = v.x + v.y + v.z + v.w;
  float s2 = v.x * v.x + v.y * v.y + v.z * v.z + v.w * v.w;
#pragma unroll
  for (int off = 32; off; off >>= 1) { s1 += __shfl_xor(s1, off); s2 += __shfl_xor(s2, off); }
  float mu = s1 * (1.0f / 256.0f);
  float var = s2 * (1.0f / 256.0f) - mu * mu;
  float rs = rsqrtf(var + 1e-5f);
  float4 g4 = ((const float4*)g)[lane];
  float4 b4 = ((const float4*)b)[lane];
  short4 o;
  o.x = f2bf((v.x - mu) * rs * g4.x + b4.x);
  o.y = f2bf((v.y - mu) * rs * g4.y + b4.y);
  o.z = f2bf((v.z - mu) * rs * g4.z + b4.z);
  o.w = f2bf((v.w - mu) * rs * g4.w + b4.w);
  *(short4*)(hb + (size_t)node * 256 + lane * 4) = o;
}

// ---- fused merge(prev) + LSTM: 64 blocks x 1024 threads; k-split x4 + LDS reduce.
//      Thread: cell = t&63, type = (t>>6)&3, kc = t>>8 -> 192-FMA chain (4x shorter). ----
__global__ __launch_bounds__(1024) void lstm_merge(const float* __restrict__ wT,
                                                   const float* __restrict__ bias,
                                                   float* __restrict__ c,
                                                   float* __restrict__ hl,
                                                   const float* __restrict__ pm,
                                                   const float* __restrict__ pden,
                                                   const float* __restrict__ pnum,
                                                   int step) {
  int blk = blockIdx.x;
  int s = blk >> 2, q = blk & 3;
  int t = threadIdx.x;
  __shared__ float Xl[768];
  __shared__ float part[4][256];
  __shared__ float gl[256];
  // --- merge r(step-1), build Xl = [h | r | h] ---
  if (step == 0) {
    if (t < 768) Xl[t] = 0.f;
    __syncthreads();
  } else {
    int dim = t & 255, pt = t >> 8;       // 4 parts x 8 slots
    float M = -INFINITY;
#pragma unroll
    for (int j = 0; j < BPS; ++j) M = fmaxf(M, pm[s * BPS + j]);
    float den = 0.f;
#pragma unroll
    for (int j = 0; j < BPS; ++j) {
      float mj = pm[s * BPS + j];
      float w = (mj == -INFINITY) ? 0.f : __expf(mj - M);
      den += w * pden[s * BPS + j];
    }
    float np = 0.f;
#pragma unroll
    for (int jj = 0; jj < 8; ++jj) {
      int j = pt * 8 + jj;
      float mj = pm[s * BPS + j];
      float w = (mj == -INFINITY) ? 0.f : __expf(mj - M);
      np += w * pnum[(size_t)(s * BPS + j) * 256 + dim];
    }
    part[pt][dim] = np;
    __syncthreads();
    if (t < 256) {
      float num = part[0][t] + part[1][t] + part[2][t] + part[3][t];
      float r = (den > 0.f) ? num / den : 0.f;
      float hv = hl[s * 256 + t];
      Xl[t] = hv; Xl[256 + t] = r; Xl[512 + t] = hv;
    }
    __syncthreads();
  }
  // --- matvec: gate g = type*256 + q*64 + cell over k-chunk kc ---
  {
    int cell = t & 63, type = (t >> 6) & 3, kc = t >> 8;
    int g = type * 256 + q * 64 + cell;
    float acc = 0.f;
    const float* wp = wT + (size_t)(kc * 192) * 1024 + g;
#pragma unroll 8
    for (int k = 0; k < 192; ++k) acc += Xl[kc * 192 + k] * wp[(size_t)k * 1024];
    part[kc][t & 255] = acc;
  }
  __syncthreads();
  if (t < 256) {
    int g = (t >> 6) * 256 + q * 64 + (t & 63);
    gl[t] = bias[g] + part[0][t] + part[1][t] + part[2][t] + part[3][t];
  }
  __syncthreads();
  if (t < 64) {
    int cl = q * 64 + t;
    float ig = gl[t], fg = gl[64 + t], gg = gl[128 + t], og = gl[192 + t];
    float cv = sigm(fg) * c[s * 256 + cl] + sigm(ig) * tanhf(gg);
    float hv = sigm(og) * tanhf(cv);
    c[s * 256 + cl] = cv;
    hl[s * 256 + cl] = hv;
  }
}

// ---- attn: 512 blocks (16 seg x 32 chunks). 16-lane group per node; bf16 h. ----
__global__ __launch_bounds__(256) void attn_kernel(const short* __restrict__ hb,
                                                   const float* __restrict__ hl,
                                                   const int* __restrict__ segb,
                                                   float* __restrict__ pm,
                                                   float* __restrict__ pden,
                                                   float* __restrict__ pnum) {
  int blk = blockIdx.x;
  int s = blk >> 5, j = blk & (BPS - 1);
  int lo = segb[s], hi = segb[s + 1];
  int cnt = hi - lo;
  int chunk = (cnt + BPS - 1) >> 5;
  int blo = lo + j * chunk;
  int bhi = min(blo + chunk, hi);
  int t = threadIdx.x;
  int gid = t >> 4, sl = t & 15;
  float qr[16];
  const float4* q4 = (const float4*)(hl + s * 256 + sl * 16);
#pragma unroll
  for (int i = 0; i < 4; ++i) {
    float4 v = q4[i];
    qr[4 * i] = v.x; qr[4 * i + 1] = v.y; qr[4 * i + 2] = v.z; qr[4 * i + 3] = v.w;
  }
  float m = -INFINITY, den = 0.f;
  float acc[16] = {};
  for (int n = blo + gid; n < bhi; n += 16) {
    const s16x8* hp = (const s16x8*)(hb + (size_t)n * 256 + sl * 16);
    s16x8 u0 = hp[0], u1 = hp[1];
    float hv[16];
#pragma unroll
    for (int k = 0; k < 8; ++k) hv[k] = bf2f((unsigned short)u0[k]);
#pragma unroll
    for (int k = 0; k < 8; ++k) hv[8 + k] = bf2f((unsigned short)u1[k]);
    float d0 = 0.f, d1 = 0.f;
#pragma unroll
    for (int k = 0; k < 8; ++k) {
      d0 = fmaf(hv[k], qr[k], d0);
      d1 = fmaf(hv[8 + k], qr[8 + k], d1);
    }
    float e = d0 + d1;
    e += __shfl_xor(e, 1); e += __shfl_xor(e, 2);
    e += __shfl_xor(e, 4); e += __shfl_xor(e, 8);
    float mn = fmaxf(m, e);
    float scl = __expf(m - mn);
    float p = __expf(e - mn);
    den = den * scl + p;
#pragma unroll
    for (int k = 0; k < 16; ++k) acc[k] = acc[k] * scl + p * hv[k];
    m = mn;
  }
  __shared__ float sm[16], sden[16], racc[16][256];
  if (sl == 0) { sm[gid] = m; sden[gid] = den; }
#pragma unroll
  for (int i = 0; i < 4; ++i)
    ((float4*)&racc[gid][sl * 16])[i] = make_float4(acc[4 * i], acc[4 * i + 1], acc[4 * i + 2], acc[4 * i + 3]);
  __syncthreads();
  float M = -INFINITY;
#pragma unroll
  for (int g = 0; g < 16; ++g) M = fmaxf(M, sm[g]);
  float D = 0.f, nm = 0.f;
  if (M > -INFINITY) {
#pragma unroll
    for (int g = 0; g < 16; ++g) {
      float w = (sm[g] == -INFINITY) ? 0.f : __expf(sm[g] - M);
      D += w * sden[g];
      nm += w * racc[g][t];
    }
  }
  if (t == 0) { pm[blk] = M; pden[blk] = D; }
  pnum[(size_t)blk * 256 + t] = nm;
}

// ---- final: blocks 0-15 merge last attn + write [q,r]; blocks 16-25 write tail ----
__global__ __launch_bounds__(256) void final_kernel(const float* __restrict__ pm,
                                                    const float* __restrict__ pden,
                                                    const float* __restrict__ pnum,
                                                    const float* __restrict__ hl,
                                                    float* __restrict__ out) {
  int blk = blockIdx.x, t = threadIdx.x;
  if (blk < 16) {
    float hv = hl[blk * 256 + t];
    float M = -INFINITY;
#pragma unroll
    for (int j = 0; j < BPS; ++j) M = fmaxf(M, pm[blk * BPS + j]);
    float den = 0.f, num = 0.f;
#pragma unroll 4
    for (int j = 0; j < BPS; ++j) {
      float mj = pm[blk * BPS + j];
      float w = (mj == -INFINITY) ? 0.f : __expf(mj - M);
      den += w * pden[blk * BPS + j];
      num += w * pnum[(size_t)(blk * BPS + j) * 256 + t];
    }
    float r = (den > 0.f) ? num / den : 0.f;
    out[blk * 512 + t] = hv;
    out[blk * 512 + 256 + t] = r;
  } else {
    int idx = 8192 + (blk - 16) * 256 + t;   // 2560 tail elems
    out[idx] = (idx >= 9728 && idx < 10240) ? (float)(idx - 9728) : 0.0f;
  }
}

extern "C" void kernel_launch(void* const* d_in, const int* in_sizes, int n_in,
                              void* d_out, int out_size, void* d_ws, size_t ws_size,
                              hipStream_t stream) {
  const float* x    = (const float*)d_in[0];
  const int*   batch= (const int*)d_in[3];
  const float* bw0  = (const float*)d_in[4];
  const float* sw0  = (const float*)d_in[5];
  const float* sc0  = (const float*)d_in[6];
  const float* bw1  = (const float*)d_in[7];
  const float* sw1  = (const float*)d_in[8];
  const float* sc1  = (const float*)d_in[9];
  const float* ln_g = (const float*)d_in[10];
  const float* ln_b = (const float*)d_in[11];
  const float* w_ih = (const float*)d_in[12];
  const float* w_hh = (const float*)d_in[13];
  const float* b_ih = (const float*)d_in[14];
  const float* b_hh = (const float*)d_in[15];
  float* ws = (float*)d_ws;

  prep_kernel<<<4549, 256, 0, stream>>>(bw0, sw0, sc0, bw1, sw1, sc1, w_ih, w_hh,
                                        b_ih, b_hh, batch, ws);
  short* Af = (short*)(ws + AF_OFF);
  expand_kernel<64><<<2048, 256, 0, stream>>>(x, Af);
  gemm_mfma<576, 128><<<dim3(512, 1), 256, 0, stream>>>(Af, (const short*)(ws + WD0_OFF), ws + H1_OFF);
  expand_kernel<128><<<2048, 256, 0, stream>>>(ws + H1_OFF, Af);
  gemm_mfma<1152, 256><<<dim3(512, 2), 256, 0, stream>>>(Af, (const short*)(ws + WD1_OFF), ws + H2_OFF);
  ln_kernel<<<16384, 256, 0, stream>>>(ws + H2_OFF, ln_g, ln_b, (short*)(ws + H2B_OFF));
  const int* segb = (const int*)(ws + SEGB_OFF);
  for (int step = 0; step < 8; ++step) {
    lstm_merge<<<64, 1024, 0, stream>>>(ws + WTIH_OFF, ws + BIAS_OFF, ws + C_OFF, ws + HL_OFF,
                                        ws + PM_OFF, ws + PDEN_OFF, ws + PNUM_OFF, step);
    attn_kernel<<<NB * BPS, 256, 0, stream>>>((const short*)(ws + H2B_OFF), ws + HL_OFF, segb,
                                              ws + PM_OFF, ws + PDEN_OFF, ws + PNUM_OFF);
  }
  final_kernel<<<26, 256, 0, stream>>>(ws + PM_OFF, ws + PDEN_OFF, ws + PNUM_OFF,
                                       ws + HL_OFF, (float*)d_out);
}

// Round 10
// 448.879 us; speedup vs baseline: 5.8277x; 1.1103x over previous
//
#include <hip/hip_runtime.h>
#include <math.h>

#define N_NODES 65536
#define NB 16
#define BPS 32   // chunks (blocks) per segment in attn

// ---- ws layout (float offsets) ----
#define WD0_OFF   0ull          // dense W0: 128*576 bf16 = 36864 f
#define WD1_OFF   36864ull      // dense W1: 256*1152 bf16 = 147456 f
#define WTIH_OFF  184320ull     // 512*1024 f (wT rows 0..511)
#define WTHH_OFF  708608ull     // 256*1024 f (wT rows 512..767, contiguous after WTIH)
#define BIAS_OFF  970752ull     // 1024 f
#define C_OFF     971776ull     // 16*256 f
#define HL_OFF    975872ull     // 16*256 f
#define SEGB_OFF  979968ull     // 17 ints (+pad)
#define PM_OFF    980000ull     // 512 f
#define PDEN_OFF  980512ull     // 512 f
#define PNUM_OFF  981024ull     // 512*256 f = 131072
#define H1_OFF    1112096ull    // N*128 f
#define H2_OFF    9500704ull    // N*256 f
#define AF_OFF    26277920ull   // 65536*1152 bf16 = 37748736 f
#define H2B_OFF   26277920ull   // N*256 bf16 (aliases AF; AF dead after gemm1)

typedef __attribute__((ext_vector_type(8))) short s16x8;
typedef __attribute__((ext_vector_type(4))) float f32x4;

__device__ __forceinline__ float sigm(float x) {
  return __builtin_amdgcn_rcpf(1.0f + __expf(-x));
}

__device__ __forceinline__ short f2bf(float f) {
  union { float f; unsigned u; } v; v.f = f;
  unsigned r = (v.u + 0x7FFFu + ((v.u >> 16) & 1u)) >> 16;
  return (short)r;
}

__device__ __forceinline__ float bf2f(unsigned short u) {
  return __uint_as_float(((unsigned)u) << 16);
}

__device__ __forceinline__ void bspline_bases(float x, float b8[8]) {
  float t[12];
#pragma unroll
  for (int i = 0; i < 12; ++i) t[i] = (float)(i - 3) * 0.4f - 1.0f;
  float b[11];
#pragma unroll
  for (int i = 0; i < 11; ++i) b[i] = (x >= t[i] && x < t[i + 1]) ? 1.0f : 0.0f;
#pragma unroll
  for (int k = 1; k <= 3; ++k) {
#pragma unroll
    for (int i = 0; i + k < 11; ++i) {
      float invl = 1.0f / (t[i + k] - t[i]);
      float invr = 1.0f / (t[i + k + 1] - t[i + 1]);
      b[i] = (x - t[i]) * invl * b[i] + (t[i + k + 1] - x) * invr * b[i + 1];
    }
  }
#pragma unroll
  for (int j = 0; j < 8; ++j) b8[j] = b[j];
}

// ---- prep: dense bf16 KAN weights, LSTM wT (f32), bias, zero c/hl, segb ----
__global__ __launch_bounds__(256) void prep_kernel(
    const float* __restrict__ bw0, const float* __restrict__ sw0, const float* __restrict__ sc0,
    const float* __restrict__ bw1, const float* __restrict__ sw1, const float* __restrict__ sc1,
    const float* __restrict__ w_ih, const float* __restrict__ w_hh,
    const float* __restrict__ b_ih, const float* __restrict__ b_hh,
    const int* __restrict__ batch,
    float* __restrict__ ws) {
  int id = blockIdx.x * 256 + threadIdx.x;
  if (id < 73728) {                        // Wd0 dense: [128][576]
    int o = id / 576, k = id % 576;
    float v;
    if (k < 64) v = bw0[o * 64 + k];
    else { int kk = k - 64, d = kk >> 3, j = kk & 7;
           v = sw0[(o * 64 + d) * 8 + j] * sc0[o * 64 + d]; }
    ((short*)(ws + WD0_OFF))[id] = f2bf(v);
  } else if (id < 368640) {                // Wd1 dense: [256][1152]
    int l = id - 73728;
    int o = l / 1152, k = l % 1152;
    float v;
    if (k < 128) v = bw1[o * 128 + k];
    else { int kk = k - 128, d = kk >> 3, j = kk & 7;
           v = sw1[(o * 128 + d) * 8 + j] * sc1[o * 128 + d]; }
    ((short*)(ws + WD1_OFF))[l] = f2bf(v);
  } else if (id < 892928) {                // wT_ih: [512][1024]
    int l = id - 368640; int k = l >> 10, g = l & 1023;
    ws[WTIH_OFF + l] = w_ih[g * 512 + k];
  } else if (id < 1155072) {               // wT_hh: [256][1024]
    int l = id - 892928; int k = l >> 10, g = l & 1023;
    ws[WTHH_OFF + l] = w_hh[g * 256 + k];
  } else if (id < 1156096) {
    int g = id - 1155072;
    ws[BIAS_OFF + g] = b_ih[g] + b_hh[g];
  } else if (id < 1164288) {
    ws[C_OFF + (id - 1156096)] = 0.0f;     // c, hl contiguous (8192 f)
  } else if (id < 1164305) {
    int s = id - 1164288;
    int lo = 0, hi = N_NODES;
    while (lo < hi) { int mid = (lo + hi) >> 1; if (batch[mid] < s) lo = mid + 1; else hi = mid; }
    ((int*)(ws + SEGB_OFF))[s] = lo;
  }
}

// ---- expansion: x[N][IN] f32 -> Af[N][9*IN] bf16 dense ----
template <int IN>
__global__ __launch_bounds__(256) void expand_kernel(const float* __restrict__ in,
                                                     short* __restrict__ Af) {
  constexpr int RS = 9 * IN;
  const int total = N_NODES * IN;
  for (int id = blockIdx.x * 256 + threadIdx.x; id < total; id += gridDim.x * 256) {
    int n = id / IN;
    int d = id & (IN - 1);
    float v = in[id];
    float sv = v * sigm(v);
    float b8[8];
    bspline_bases(v, b8);
    short* rowp = Af + (size_t)n * RS;
    rowp[d] = f2bf(sv);
    s16x8 q;
#pragma unroll
    for (int j = 0; j < 8; ++j) q[j] = f2bf(b8[j]);
    ((s16x8*)(rowp + IN))[d] = q;
  }
}

// ---- pure GEMM: out[N][OUT] = A[N][K]bf16 @ W[OUT][K]bf16^T. BK=64, 128x128 tile.
//      Staging: row-major slots (8 lanes = one row's contiguous 128B -> coalesced),
//      XOR-swizzled k-group (rule #21: linear LDS dest + inverse-swz per-lane SOURCE
//      + swz on ds_read). 32KB LDS -> 4 blocks/CU. ----
template <int K, int OUT>
__global__ __launch_bounds__(256, 2) void gemm_mfma(const short* __restrict__ A,
                                                    const short* __restrict__ Wp,
                                                    float* __restrict__ out) {
  constexpr int CHUNKS = K / 64;
  __shared__ s16x8 As[1024];   // 16 KB: slot = row*8 + kgp, kgp = kg ^ (row&7)
  __shared__ s16x8 Bs[1024];   // 16 KB
  const int tid = threadIdx.x;
  const int n0 = blockIdx.x * 128;
  const int nb0 = blockIdx.y * 128;
  const int lane = tid & 63;
  const int wid = tid >> 6;
  const int wr = wid >> 1, wc = wid & 1;
  const int l15 = lane & 15, l4 = lane >> 4;
  const int x7 = l15 & 7;

  f32x4 acc[4][4] = {};

  for (int c = 0; c < CHUNKS; ++c) {
    if (c) __syncthreads();
#pragma unroll
    for (int i = 0; i < 4; ++i) {
      int s = i * 256 + tid;
      int row = s >> 3, kgp = s & 7;
      int kg = kgp ^ (row & 7);        // inverse-swizzled global source (XOR involution)
      __builtin_amdgcn_global_load_lds(
          (const __attribute__((address_space(1))) unsigned int*)(A + (size_t)(n0 + row) * K + c * 64 + kg * 8),
          (__attribute__((address_space(3))) unsigned int*)&As[s], 16, 0, 0);
      __builtin_amdgcn_global_load_lds(
          (const __attribute__((address_space(1))) unsigned int*)(Wp + (size_t)(nb0 + row) * K + c * 64 + kg * 8),
          (__attribute__((address_space(3))) unsigned int*)&Bs[s], 16, 0, 0);
    }
    __syncthreads();   // drains vmcnt before any wave reads LDS
#pragma unroll
    for (int kk = 0; kk < 2; ++kk) {
      s16x8 a[4], b[4];
      const int kq = kk * 4 + l4;
#pragma unroll
      for (int mi = 0; mi < 4; ++mi) {
        int row = wr * 64 + mi * 16 + l15;
        a[mi] = As[row * 8 + (kq ^ x7)];
      }
#pragma unroll
      for (int ni = 0; ni < 4; ++ni) {
        int col = wc * 64 + ni * 16 + l15;
        b[ni] = Bs[col * 8 + (kq ^ x7)];
      }
#pragma unroll
      for (int mi = 0; mi < 4; ++mi)
#pragma unroll
        for (int ni = 0; ni < 4; ++ni)
          acc[mi][ni] = __builtin_amdgcn_mfma_f32_16x16x32_bf16(a[mi], b[ni], acc[mi][ni], 0, 0, 0);
    }
  }
  // epilogue: C col = lane&15, row = (lane>>4)*4 + reg
#pragma unroll
  for (int mi = 0; mi < 4; ++mi) {
#pragma unroll
    for (int r = 0; r < 4; ++r) {
      int m = wr * 64 + mi * 16 + l4 * 4 + r;
      float* orow = out + (size_t)(n0 + m) * OUT + nb0;
#pragma unroll
      for (int ni = 0; ni < 4; ++ni)
        orow[wc * 64 + ni * 16 + l15] = acc[mi][ni][r];
    }
  }
}

// ---- LayerNorm over 256 dims, one wave per node; f32 in -> bf16 out ----
__global__ __launch_bounds__(256) void ln_kernel(const float* __restrict__ h,
                                                 const float* __restrict__ g,
                                                 const float* __restrict__ b,
                                                 short* __restrict__ hb) {
  int gid = blockIdx.x * 256 + threadIdx.x;
  int node = gid >> 6;
  int lane = gid & 63;
  const float4* row = (const float4*)(h + (size_t)node * 256);
  float4 v = row[lane];
  float s1 = v.x + v.y + v.z + v.w;
  float s2 = v.x * v.x + v.y * v.y + v.z * v.z + v.w * v.w;
#pragma unroll
  for (int off = 32; off; off >>= 1) { s1 += __shfl_xor(s1, off); s2 += __shfl_xor(s2, off); }
  float mu = s1 * (1.0f / 256.0f);
  float var = s2 * (1.0f / 256.0f) - mu * mu;
  float rs = rsqrtf(var + 1e-5f);
  float4 g4 = ((const float4*)g)[lane];
  float4 b4 = ((const float4*)b)[lane];
  short4 o;
  o.x = f2bf((v.x - mu) * rs * g4.x + b4.x);
  o.y = f2bf((v.y - mu) * rs * g4.y + b4.y);
  o.z = f2bf((v.z - mu) * rs * g4.z + b4.z);
  o.w = f2bf((v.w - mu) * rs * g4.w + b4.w);
  *(short4*)(hb + (size_t)node * 256 + lane * 4) = o;
}

// ---- fused merge(prev) + LSTM: 64 blocks x 1024 threads; k-split x4 + LDS reduce ----
__global__ __launch_bounds__(1024) void lstm_merge(const float* __restrict__ wT,
                                                   const float* __restrict__ bias,
                                                   float* __restrict__ c,
                                                   float* __restrict__ hl,
                                                   const float* __restrict__ pm,
                                                   const float* __restrict__ pden,
                                                   const float* __restrict__ pnum,
                                                   int step) {
  int blk = blockIdx.x;
  int s = blk >> 2, q = blk & 3;
  int t = threadIdx.x;
  __shared__ float Xl[768];
  __shared__ float part[4][256];
  __shared__ float gl[256];
  if (step == 0) {
    if (t < 768) Xl[t] = 0.f;
    __syncthreads();
  } else {
    int dim = t & 255, pt = t >> 8;       // 4 parts x 8 slots
    float M = -INFINITY;
#pragma unroll
    for (int j = 0; j < BPS; ++j) M = fmaxf(M, pm[s * BPS + j]);
    float den = 0.f;
#pragma unroll
    for (int j = 0; j < BPS; ++j) {
      float mj = pm[s * BPS + j];
      float w = (mj == -INFINITY) ? 0.f : __expf(mj - M);
      den += w * pden[s * BPS + j];
    }
    float np = 0.f;
#pragma unroll
    for (int jj = 0; jj < 8; ++jj) {
      int j = pt * 8 + jj;
      float mj = pm[s * BPS + j];
      float w = (mj == -INFINITY) ? 0.f : __expf(mj - M);
      np += w * pnum[(size_t)(s * BPS + j) * 256 + dim];
    }
    part[pt][dim] = np;
    __syncthreads();
    if (t < 256) {
      float num = part[0][t] + part[1][t] + part[2][t] + part[3][t];
      float r = (den > 0.f) ? num / den : 0.f;
      float hv = hl[s * 256 + t];
      Xl[t] = hv; Xl[256 + t] = r; Xl[512 + t] = hv;
    }
    __syncthreads();
  }
  {
    int cell = t & 63, type = (t >> 6) & 3, kc = t >> 8;
    int g = type * 256 + q * 64 + cell;
    float acc = 0.f;
    const float* wp = wT + (size_t)(kc * 192) * 1024 + g;
#pragma unroll 8
    for (int k = 0; k < 192; ++k) acc += Xl[kc * 192 + k] * wp[(size_t)k * 1024];
    part[kc][t & 255] = acc;
  }
  __syncthreads();
  if (t < 256) {
    int g = (t >> 6) * 256 + q * 64 + (t & 63);
    gl[t] = bias[g] + part[0][t] + part[1][t] + part[2][t] + part[3][t];
  }
  __syncthreads();
  if (t < 64) {
    int cl = q * 64 + t;
    float ig = gl[t], fg = gl[64 + t], gg = gl[128 + t], og = gl[192 + t];
    float cv = sigm(fg) * c[s * 256 + cl] + sigm(ig) * tanhf(gg);
    float hv = sigm(og) * tanhf(cv);
    c[s * 256 + cl] = cv;
    hl[s * 256 + cl] = hv;
  }
}

// ---- attn: 512 blocks (16 seg x 32 chunks). 16-lane group per node; bf16 h. ----
__global__ __launch_bounds__(256) void attn_kernel(const short* __restrict__ hb,
                                                   const float* __restrict__ hl,
                                                   const int* __restrict__ segb,
                                                   float* __restrict__ pm,
                                                   float* __restrict__ pden,
                                                   float* __restrict__ pnum) {
  int blk = blockIdx.x;
  int s = blk >> 5, j = blk & (BPS - 1);
  int lo = segb[s], hi = segb[s + 1];
  int cnt = hi - lo;
  int chunk = (cnt + BPS - 1) >> 5;
  int blo = lo + j * chunk;
  int bhi = min(blo + chunk, hi);
  int t = threadIdx.x;
  int gid = t >> 4, sl = t & 15;
  float qr[16];
  const float4* q4 = (const float4*)(hl + s * 256 + sl * 16);
#pragma unroll
  for (int i = 0; i < 4; ++i) {
    float4 v = q4[i];
    qr[4 * i] = v.x; qr[4 * i + 1] = v.y; qr[4 * i + 2] = v.z; qr[4 * i + 3] = v.w;
  }
  float m = -INFINITY, den = 0.f;
  float acc[16] = {};
  for (int n = blo + gid; n < bhi; n += 16) {
    const s16x8* hp = (const s16x8*)(hb + (size_t)n * 256 + sl * 16);
    s16x8 u0 = hp[0], u1 = hp[1];
    float hv[16];
#pragma unroll
    for (int k = 0; k < 8; ++k) hv[k] = bf2f((unsigned short)u0[k]);
#pragma unroll
    for (int k = 0; k < 8; ++k) hv[8 + k] = bf2f((unsigned short)u1[k]);
    float d0 = 0.f, d1 = 0.f;
#pragma unroll
    for (int k = 0; k < 8; ++k) {
      d0 = fmaf(hv[k], qr[k], d0);
      d1 = fmaf(hv[8 + k], qr[8 + k], d1);
    }
    float e = d0 + d1;
    e += __shfl_xor(e, 1); e += __shfl_xor(e, 2);
    e += __shfl_xor(e, 4); e += __shfl_xor(e, 8);
    float mn = fmaxf(m, e);
    float scl = __expf(m - mn);
    float p = __expf(e - mn);
    den = den * scl + p;
#pragma unroll
    for (int k = 0; k < 16; ++k) acc[k] = acc[k] * scl + p * hv[k];
    m = mn;
  }
  __shared__ float sm[16], sden[16], racc[16][256];
  if (sl == 0) { sm[gid] = m; sden[gid] = den; }
#pragma unroll
  for (int i = 0; i < 4; ++i)
    ((float4*)&racc[gid][sl * 16])[i] = make_float4(acc[4 * i], acc[4 * i + 1], acc[4 * i + 2], acc[4 * i + 3]);
  __syncthreads();
  float M = -INFINITY;
#pragma unroll
  for (int g = 0; g < 16; ++g) M = fmaxf(M, sm[g]);
  float D = 0.f, nm = 0.f;
  if (M > -INFINITY) {
#pragma unroll
    for (int g = 0; g < 16; ++g) {
      float w = (sm[g] == -INFINITY) ? 0.f : __expf(sm[g] - M);
      D += w * sden[g];
      nm += w * racc[g][t];
    }
  }
  if (t == 0) { pm[blk] = M; pden[blk] = D; }
  pnum[(size_t)blk * 256 + t] = nm;
}

// ---- final: blocks 0-15 merge last attn + write [q,r]; blocks 16-25 write tail ----
__global__ __launch_bounds__(256) void final_kernel(const float* __restrict__ pm,
                                                    const float* __restrict__ pden,
                                                    const float* __restrict__ pnum,
                                                    const float* __restrict__ hl,
                                                    float* __restrict__ out) {
  int blk = blockIdx.x, t = threadIdx.x;
  if (blk < 16) {
    float hv = hl[blk * 256 + t];
    float M = -INFINITY;
#pragma unroll
    for (int j = 0; j < BPS; ++j) M = fmaxf(M, pm[blk * BPS + j]);
    float den = 0.f, num = 0.f;
#pragma unroll 4
    for (int j = 0; j < BPS; ++j) {
      float mj = pm[blk * BPS + j];
      float w = (mj == -INFINITY) ? 0.f : __expf(mj - M);
      den += w * pden[blk * BPS + j];
      num += w * pnum[(size_t)(blk * BPS + j) * 256 + t];
    }
    float r = (den > 0.f) ? num / den : 0.f;
    out[blk * 512 + t] = hv;
    out[blk * 512 + 256 + t] = r;
  } else {
    int idx = 8192 + (blk - 16) * 256 + t;   // 2560 tail elems
    out[idx] = (idx >= 9728 && idx < 10240) ? (float)(idx - 9728) : 0.0f;
  }
}

extern "C" void kernel_launch(void* const* d_in, const int* in_sizes, int n_in,
                              void* d_out, int out_size, void* d_ws, size_t ws_size,
                              hipStream_t stream) {
  const float* x    = (const float*)d_in[0];
  const int*   batch= (const int*)d_in[3];
  const float* bw0  = (const float*)d_in[4];
  const float* sw0  = (const float*)d_in[5];
  const float* sc0  = (const float*)d_in[6];
  const float* bw1  = (const float*)d_in[7];
  const float* sw1  = (const float*)d_in[8];
  const float* sc1  = (const float*)d_in[9];
  const float* ln_g = (const float*)d_in[10];
  const float* ln_b = (const float*)d_in[11];
  const float* w_ih = (const float*)d_in[12];
  const float* w_hh = (const float*)d_in[13];
  const float* b_ih = (const float*)d_in[14];
  const float* b_hh = (const float*)d_in[15];
  float* ws = (float*)d_ws;

  prep_kernel<<<4549, 256, 0, stream>>>(bw0, sw0, sc0, bw1, sw1, sc1, w_ih, w_hh,
                                        b_ih, b_hh, batch, ws);
  short* Af = (short*)(ws + AF_OFF);
  expand_kernel<64><<<2048, 256, 0, stream>>>(x, Af);
  gemm_mfma<576, 128><<<dim3(512, 1), 256, 0, stream>>>(Af, (const short*)(ws + WD0_OFF), ws + H1_OFF);
  expand_kernel<128><<<2048, 256, 0, stream>>>(ws + H1_OFF, Af);
  gemm_mfma<1152, 256><<<dim3(512, 2), 256, 0, stream>>>(Af, (const short*)(ws + WD1_OFF), ws + H2_OFF);
  ln_kernel<<<16384, 256, 0, stream>>>(ws + H2_OFF, ln_g, ln_b, (short*)(ws + H2B_OFF));
  const int* segb = (const int*)(ws + SEGB_OFF);
  for (int step = 0; step < 8; ++step) {
    lstm_merge<<<64, 1024, 0, stream>>>(ws + WTIH_OFF, ws + BIAS_OFF, ws + C_OFF, ws + HL_OFF,
                                        ws + PM_OFF, ws + PDEN_OFF, ws + PNUM_OFF, step);
    attn_kernel<<<NB * BPS, 256, 0, stream>>>((const short*)(ws + H2B_OFF), ws + HL_OFF, segb,
                                              ws + PM_OFF, ws + PDEN_OFF, ws + PNUM_OFF);
  }
  final_kernel<<<26, 256, 0, stream>>>(ws + PM_OFF, ws + PDEN_OFF, ws + PNUM_OFF,
                                       ws + HL_OFF, (float*)d_out);
}

// Round 11
// 447.532 us; speedup vs baseline: 5.8453x; 1.0030x over previous
//
#include <hip/hip_runtime.h>
#include <math.h>

#define N_NODES 65536
#define NB 16
#define BPS 32   // chunks (blocks) per segment in attn

// ---- ws layout (float offsets) ----
#define WD0_OFF   0ull          // dense W0: 128*576 bf16 = 36864 f
#define WD1_OFF   36864ull      // dense W1: 256*1152 bf16 = 147456 f
#define WTIH_OFF  184320ull     // 512*1024 f (wT rows 0..511)
#define WTHH_OFF  708608ull     // 256*1024 f (wT rows 512..767, contiguous after WTIH)
#define BIAS_OFF  970752ull     // 1024 f
#define C_OFF     971776ull     // 16*256 f
#define HL_OFF    975872ull     // 16*256 f
#define SEGB_OFF  979968ull     // 17 ints (+pad)
#define PM_OFF    980000ull     // 512 f
#define PDEN_OFF  980512ull     // 512 f
#define PNUM_OFF  981024ull     // 512*256 f = 131072
#define H1_OFF    1112096ull    // N*128 f
#define H2_OFF    9500704ull    // N*256 f
#define AF_OFF    26277920ull   // strip buffer: 32768*1152 bf16 = 18874368 f (reused per strip)
#define H2B_OFF   26277920ull   // N*256 bf16 (aliases AF; AF dead after gemm1 strips)

typedef __attribute__((ext_vector_type(8))) short s16x8;
typedef __attribute__((ext_vector_type(4))) float f32x4;

__device__ __forceinline__ float sigm(float x) {
  return __builtin_amdgcn_rcpf(1.0f + __expf(-x));
}

__device__ __forceinline__ short f2bf(float f) {
  union { float f; unsigned u; } v; v.f = f;
  unsigned r = (v.u + 0x7FFFu + ((v.u >> 16) & 1u)) >> 16;
  return (short)r;
}

__device__ __forceinline__ float bf2f(unsigned short u) {
  return __uint_as_float(((unsigned)u) << 16);
}

__device__ __forceinline__ void bspline_bases(float x, float b8[8]) {
  float t[12];
#pragma unroll
  for (int i = 0; i < 12; ++i) t[i] = (float)(i - 3) * 0.4f - 1.0f;
  float b[11];
#pragma unroll
  for (int i = 0; i < 11; ++i) b[i] = (x >= t[i] && x < t[i + 1]) ? 1.0f : 0.0f;
#pragma unroll
  for (int k = 1; k <= 3; ++k) {
#pragma unroll
    for (int i = 0; i + k < 11; ++i) {
      float invl = 1.0f / (t[i + k] - t[i]);
      float invr = 1.0f / (t[i + k + 1] - t[i + 1]);
      b[i] = (x - t[i]) * invl * b[i] + (t[i + k + 1] - x) * invr * b[i + 1];
    }
  }
#pragma unroll
  for (int j = 0; j < 8; ++j) b8[j] = b[j];
}

// ---- prep: dense bf16 KAN weights, LSTM wT (f32), bias, zero c/hl, segb ----
__global__ __launch_bounds__(256) void prep_kernel(
    const float* __restrict__ bw0, const float* __restrict__ sw0, const float* __restrict__ sc0,
    const float* __restrict__ bw1, const float* __restrict__ sw1, const float* __restrict__ sc1,
    const float* __restrict__ w_ih, const float* __restrict__ w_hh,
    const float* __restrict__ b_ih, const float* __restrict__ b_hh,
    const int* __restrict__ batch,
    float* __restrict__ ws) {
  int id = blockIdx.x * 256 + threadIdx.x;
  if (id < 73728) {                        // Wd0 dense: [128][576]
    int o = id / 576, k = id % 576;
    float v;
    if (k < 64) v = bw0[o * 64 + k];
    else { int kk = k - 64, d = kk >> 3, j = kk & 7;
           v = sw0[(o * 64 + d) * 8 + j] * sc0[o * 64 + d]; }
    ((short*)(ws + WD0_OFF))[id] = f2bf(v);
  } else if (id < 368640) {                // Wd1 dense: [256][1152]
    int l = id - 73728;
    int o = l / 1152, k = l % 1152;
    float v;
    if (k < 128) v = bw1[o * 128 + k];
    else { int kk = k - 128, d = kk >> 3, j = kk & 7;
           v = sw1[(o * 128 + d) * 8 + j] * sc1[o * 128 + d]; }
    ((short*)(ws + WD1_OFF))[l] = f2bf(v);
  } else if (id < 892928) {                // wT_ih: [512][1024]
    int l = id - 368640; int k = l >> 10, g = l & 1023;
    ws[WTIH_OFF + l] = w_ih[g * 512 + k];
  } else if (id < 1155072) {               // wT_hh: [256][1024]
    int l = id - 892928; int k = l >> 10, g = l & 1023;
    ws[WTHH_OFF + l] = w_hh[g * 256 + k];
  } else if (id < 1156096) {
    int g = id - 1155072;
    ws[BIAS_OFF + g] = b_ih[g] + b_hh[g];
  } else if (id < 1164288) {
    ws[C_OFF + (id - 1156096)] = 0.0f;     // c, hl contiguous (8192 f)
  } else if (id < 1164305) {
    int s = id - 1164288;
    int lo = 0, hi = N_NODES;
    while (lo < hi) { int mid = (lo + hi) >> 1; if (batch[mid] < s) lo = mid + 1; else hi = mid; }
    ((int*)(ws + SEGB_OFF))[s] = lo;
  }
}

// ---- expansion: in rows [row0, row0+nrows) -> Af[local_n][9*IN] bf16 dense ----
template <int IN>
__global__ __launch_bounds__(256) void expand_kernel(const float* __restrict__ in,
                                                     short* __restrict__ Af,
                                                     int row0, int nrows) {
  constexpr int RS = 9 * IN;
  const int total = nrows * IN;
  for (int id = blockIdx.x * 256 + threadIdx.x; id < total; id += gridDim.x * 256) {
    int n = id / IN;             // local row
    int d = id & (IN - 1);
    float v = in[(size_t)(row0 + n) * IN + d];
    float sv = v * sigm(v);
    float b8[8];
    bspline_bases(v, b8);
    short* rowp = Af + (size_t)n * RS;
    rowp[d] = f2bf(sv);
    s16x8 q;
#pragma unroll
    for (int j = 0; j < 8; ++j) q[j] = f2bf(b8[j]);
    ((s16x8*)(rowp + IN))[d] = q;
  }
}

// ---- pure GEMM: out[n0+:128][nb0+:128] = A @ W^T. BK=64, coalesced row-major staging,
//      XOR-swizzled k-group (rule #21), 32KB LDS. ----
template <int K, int OUT>
__global__ __launch_bounds__(256, 2) void gemm_mfma(const short* __restrict__ A,
                                                    const short* __restrict__ Wp,
                                                    float* __restrict__ out) {
  constexpr int CHUNKS = K / 64;
  __shared__ s16x8 As[1024];   // 16 KB: slot = row*8 + kgp, kgp = kg ^ (row&7)
  __shared__ s16x8 Bs[1024];   // 16 KB
  const int tid = threadIdx.x;
  const int n0 = blockIdx.x * 128;
  const int nb0 = blockIdx.y * 128;
  const int lane = tid & 63;
  const int wid = tid >> 6;
  const int wr = wid >> 1, wc = wid & 1;
  const int l15 = lane & 15, l4 = lane >> 4;
  const int x7 = l15 & 7;

  f32x4 acc[4][4] = {};

  for (int c = 0; c < CHUNKS; ++c) {
    if (c) __syncthreads();
#pragma unroll
    for (int i = 0; i < 4; ++i) {
      int s = i * 256 + tid;
      int row = s >> 3, kgp = s & 7;
      int kg = kgp ^ (row & 7);        // inverse-swizzled global source (XOR involution)
      __builtin_amdgcn_global_load_lds(
          (const __attribute__((address_space(1))) unsigned int*)(A + (size_t)(n0 + row) * K + c * 64 + kg * 8),
          (__attribute__((address_space(3))) unsigned int*)&As[s], 16, 0, 0);
      __builtin_amdgcn_global_load_lds(
          (const __attribute__((address_space(1))) unsigned int*)(Wp + (size_t)(nb0 + row) * K + c * 64 + kg * 8),
          (__attribute__((address_space(3))) unsigned int*)&Bs[s], 16, 0, 0);
    }
    __syncthreads();   // drains vmcnt before any wave reads LDS
#pragma unroll
    for (int kk = 0; kk < 2; ++kk) {
      s16x8 a[4], b[4];
      const int kq = kk * 4 + l4;
#pragma unroll
      for (int mi = 0; mi < 4; ++mi) {
        int row = wr * 64 + mi * 16 + l15;
        a[mi] = As[row * 8 + (kq ^ x7)];
      }
#pragma unroll
      for (int ni = 0; ni < 4; ++ni) {
        int col = wc * 64 + ni * 16 + l15;
        b[ni] = Bs[col * 8 + (kq ^ x7)];
      }
#pragma unroll
      for (int mi = 0; mi < 4; ++mi)
#pragma unroll
        for (int ni = 0; ni < 4; ++ni)
          acc[mi][ni] = __builtin_amdgcn_mfma_f32_16x16x32_bf16(a[mi], b[ni], acc[mi][ni], 0, 0, 0);
    }
  }
  // epilogue: C col = lane&15, row = (lane>>4)*4 + reg
#pragma unroll
  for (int mi = 0; mi < 4; ++mi) {
#pragma unroll
    for (int r = 0; r < 4; ++r) {
      int m = wr * 64 + mi * 16 + l4 * 4 + r;
      float* orow = out + (size_t)(n0 + m) * OUT + nb0;
#pragma unroll
      for (int ni = 0; ni < 4; ++ni)
        orow[wc * 64 + ni * 16 + l15] = acc[mi][ni][r];
    }
  }
}

// ---- LayerNorm over 256 dims, one wave per node; f32 in -> bf16 out ----
__global__ __launch_bounds__(256) void ln_kernel(const float* __restrict__ h,
                                                 const float* __restrict__ g,
                                                 const float* __restrict__ b,
                                                 short* __restrict__ hb) {
  int gid = blockIdx.x * 256 + threadIdx.x;
  int node = gid >> 6;
  int lane = gid & 63;
  const float4* row = (const float4*)(h + (size_t)node * 256);
  float4 v = row[lane];
  float s1 = v.x + v.y + v.z + v.w;
  float s2 = v.x * v.x + v.y * v.y + v.z * v.z + v.w * v.w;
#pragma unroll
  for (int off = 32; off; off >>= 1) { s1 += __shfl_xor(s1, off); s2 += __shfl_xor(s2, off); }
  float mu = s1 * (1.0f / 256.0f);
  float var = s2 * (1.0f / 256.0f) - mu * mu;
  float rs = rsqrtf(var + 1e-5f);
  float4 g4 = ((const float4*)g)[lane];
  float4 b4 = ((const float4*)b)[lane];
  short4 o;
  o.x = f2bf((v.x - mu) * rs * g4.x + b4.x);
  o.y = f2bf((v.y - mu) * rs * g4.y + b4.y);
  o.z = f2bf((v.z - mu) * rs * g4.z + b4.z);
  o.w = f2bf((v.w - mu) * rs * g4.w + b4.w);
  *(short4*)(hb + (size_t)node * 256 + lane * 4) = o;
}

// ---- fused merge(prev) + LSTM: 64 blocks x 1024 threads; k-split x4 + LDS reduce ----
__global__ __launch_bounds__(1024) void lstm_merge(const float* __restrict__ wT,
                                                   const float* __restrict__ bias,
                                                   float* __restrict__ c,
                                                   float* __restrict__ hl,
                                                   const float* __restrict__ pm,
                                                   const float* __restrict__ pden,
                                                   const float* __restrict__ pnum,
                                                   int step) {
  int blk = blockIdx.x;
  int s = blk >> 2, q = blk & 3;
  int t = threadIdx.x;
  __shared__ float Xl[768];
  __shared__ float part[4][256];
  __shared__ float gl[256];
  if (step == 0) {
    if (t < 768) Xl[t] = 0.f;
    __syncthreads();
  } else {
    int dim = t & 255, pt = t >> 8;       // 4 parts x 8 slots
    float M = -INFINITY;
#pragma unroll
    for (int j = 0; j < BPS; ++j) M = fmaxf(M, pm[s * BPS + j]);
    float den = 0.f;
#pragma unroll
    for (int j = 0; j < BPS; ++j) {
      float mj = pm[s * BPS + j];
      float w = (mj == -INFINITY) ? 0.f : __expf(mj - M);
      den += w * pden[s * BPS + j];
    }
    float np = 0.f;
#pragma unroll
    for (int jj = 0; jj < 8; ++jj) {
      int j = pt * 8 + jj;
      float mj = pm[s * BPS + j];
      float w = (mj == -INFINITY) ? 0.f : __expf(mj - M);
      np += w * pnum[(size_t)(s * BPS + j) * 256 + dim];
    }
    part[pt][dim] = np;
    __syncthreads();
    if (t < 256) {
      float num = part[0][t] + part[1][t] + part[2][t] + part[3][t];
      float r = (den > 0.f) ? num / den : 0.f;
      float hv = hl[s * 256 + t];
      Xl[t] = hv; Xl[256 + t] = r; Xl[512 + t] = hv;
    }
    __syncthreads();
  }
  {
    int cell = t & 63, type = (t >> 6) & 3, kc = t >> 8;
    int g = type * 256 + q * 64 + cell;
    float acc = 0.f;
    const float* wp = wT + (size_t)(kc * 192) * 1024 + g;
#pragma unroll 8
    for (int k = 0; k < 192; ++k) acc += Xl[kc * 192 + k] * wp[(size_t)k * 1024];
    part[kc][t & 255] = acc;
  }
  __syncthreads();
  if (t < 256) {
    int g = (t >> 6) * 256 + q * 64 + (t & 63);
    gl[t] = bias[g] + part[0][t] + part[1][t] + part[2][t] + part[3][t];
  }
  __syncthreads();
  if (t < 64) {
    int cl = q * 64 + t;
    float ig = gl[t], fg = gl[64 + t], gg = gl[128 + t], og = gl[192 + t];
    float cv = sigm(fg) * c[s * 256 + cl] + sigm(ig) * tanhf(gg);
    float hv = sigm(og) * tanhf(cv);
    c[s * 256 + cl] = cv;
    hl[s * 256 + cl] = hv;
  }
}

// ---- attn: 512 blocks (16 seg x 32 chunks). 16-lane group per node; bf16 h. ----
__global__ __launch_bounds__(256) void attn_kernel(const short* __restrict__ hb,
                                                   const float* __restrict__ hl,
                                                   const int* __restrict__ segb,
                                                   float* __restrict__ pm,
                                                   float* __restrict__ pden,
                                                   float* __restrict__ pnum) {
  int blk = blockIdx.x;
  int s = blk >> 5, j = blk & (BPS - 1);
  int lo = segb[s], hi = segb[s + 1];
  int cnt = hi - lo;
  int chunk = (cnt + BPS - 1) >> 5;
  int blo = lo + j * chunk;
  int bhi = min(blo + chunk, hi);
  int t = threadIdx.x;
  int gid = t >> 4, sl = t & 15;
  float qr[16];
  const float4* q4 = (const float4*)(hl + s * 256 + sl * 16);
#pragma unroll
  for (int i = 0; i < 4; ++i) {
    float4 v = q4[i];
    qr[4 * i] = v.x; qr[4 * i + 1] = v.y; qr[4 * i + 2] = v.z; qr[4 * i + 3] = v.w;
  }
  float m = -INFINITY, den = 0.f;
  float acc[16] = {};
  for (int n = blo + gid; n < bhi; n += 16) {
    const s16x8* hp = (const s16x8*)(hb + (size_t)n * 256 + sl * 16);
    s16x8 u0 = hp[0], u1 = hp[1];
    float hv[16];
#pragma unroll
    for (int k = 0; k < 8; ++k) hv[k] = bf2f((unsigned short)u0[k]);
#pragma unroll
    for (int k = 0; k < 8; ++k) hv[8 + k] = bf2f((unsigned short)u1[k]);
    float d0 = 0.f, d1 = 0.f;
#pragma unroll
    for (int k = 0; k < 8; ++k) {
      d0 = fmaf(hv[k], qr[k], d0);
      d1 = fmaf(hv[8 + k], qr[8 + k], d1);
    }
    float e = d0 + d1;
    e += __shfl_xor(e, 1); e += __shfl_xor(e, 2);
    e += __shfl_xor(e, 4); e += __shfl_xor(e, 8);
    float mn = fmaxf(m, e);
    float scl = __expf(m - mn);
    float p = __expf(e - mn);
    den = den * scl + p;
#pragma unroll
    for (int k = 0; k < 16; ++k) acc[k] = acc[k] * scl + p * hv[k];
    m = mn;
  }
  __shared__ float sm[16], sden[16], racc[16][256];
  if (sl == 0) { sm[gid] = m; sden[gid] = den; }
#pragma unroll
  for (int i = 0; i < 4; ++i)
    ((float4*)&racc[gid][sl * 16])[i] = make_float4(acc[4 * i], acc[4 * i + 1], acc[4 * i + 2], acc[4 * i + 3]);
  __syncthreads();
  float M = -INFINITY;
#pragma unroll
  for (int g = 0; g < 16; ++g) M = fmaxf(M, sm[g]);
  float D = 0.f, nm = 0.f;
  if (M > -INFINITY) {
#pragma unroll
    for (int g = 0; g < 16; ++g) {
      float w = (sm[g] == -INFINITY) ? 0.f : __expf(sm[g] - M);
      D += w * sden[g];
      nm += w * racc[g][t];
    }
  }
  if (t == 0) { pm[blk] = M; pden[blk] = D; }
  pnum[(size_t)blk * 256 + t] = nm;
}

// ---- final: blocks 0-15 merge last attn + write [q,r]; blocks 16-25 write tail ----
__global__ __launch_bounds__(256) void final_kernel(const float* __restrict__ pm,
                                                    const float* __restrict__ pden,
                                                    const float* __restrict__ pnum,
                                                    const float* __restrict__ hl,
                                                    float* __restrict__ out) {
  int blk = blockIdx.x, t = threadIdx.x;
  if (blk < 16) {
    float hv = hl[blk * 256 + t];
    float M = -INFINITY;
#pragma unroll
    for (int j = 0; j < BPS; ++j) M = fmaxf(M, pm[blk * BPS + j]);
    float den = 0.f, num = 0.f;
#pragma unroll 4
    for (int j = 0; j < BPS; ++j) {
      float mj = pm[blk * BPS + j];
      float w = (mj == -INFINITY) ? 0.f : __expf(mj - M);
      den += w * pden[blk * BPS + j];
      num += w * pnum[(size_t)(blk * BPS + j) * 256 + t];
    }
    float r = (den > 0.f) ? num / den : 0.f;
    out[blk * 512 + t] = hv;
    out[blk * 512 + 256 + t] = r;
  } else {
    int idx = 8192 + (blk - 16) * 256 + t;   // 2560 tail elems
    out[idx] = (idx >= 9728 && idx < 10240) ? (float)(idx - 9728) : 0.0f;
  }
}

extern "C" void kernel_launch(void* const* d_in, const int* in_sizes, int n_in,
                              void* d_out, int out_size, void* d_ws, size_t ws_size,
                              hipStream_t stream) {
  const float* x    = (const float*)d_in[0];
  const int*   batch= (const int*)d_in[3];
  const float* bw0  = (const float*)d_in[4];
  const float* sw0  = (const float*)d_in[5];
  const float* sc0  = (const float*)d_in[6];
  const float* bw1  = (const float*)d_in[7];
  const float* sw1  = (const float*)d_in[8];
  const float* sc1  = (const float*)d_in[9];
  const float* ln_g = (const float*)d_in[10];
  const float* ln_b = (const float*)d_in[11];
  const float* w_ih = (const float*)d_in[12];
  const float* w_hh = (const float*)d_in[13];
  const float* b_ih = (const float*)d_in[14];
  const float* b_hh = (const float*)d_in[15];
  float* ws = (float*)d_ws;

  prep_kernel<<<4549, 256, 0, stream>>>(bw0, sw0, sc0, bw1, sw1, sc1, w_ih, w_hh,
                                        b_ih, b_hh, batch, ws);
  short* Af = (short*)(ws + AF_OFF);
  // layer 0: single pass (Af0 = 75 MB, L3-resident between expand and gemm)
  expand_kernel<64><<<2048, 256, 0, stream>>>(x, Af, 0, N_NODES);
  gemm_mfma<576, 128><<<dim3(512, 1), 256, 0, stream>>>(Af, (const short*)(ws + WD0_OFF), ws + H1_OFF);
  // layer 1: 2 strips of 32768 rows; strip Af = 75.5 MB stays L3-resident, buffer reused
  for (int strip = 0; strip < 2; ++strip) {
    int row0 = strip * 32768;
    expand_kernel<128><<<2048, 256, 0, stream>>>(ws + H1_OFF, Af, row0, 32768);
    gemm_mfma<1152, 256><<<dim3(256, 2), 256, 0, stream>>>(Af, (const short*)(ws + WD1_OFF),
                                                           ws + H2_OFF + (size_t)row0 * 256);
  }
  ln_kernel<<<16384, 256, 0, stream>>>(ws + H2_OFF, ln_g, ln_b, (short*)(ws + H2B_OFF));
  const int* segb = (const int*)(ws + SEGB_OFF);
  for (int step = 0; step < 8; ++step) {
    lstm_merge<<<64, 1024, 0, stream>>>(ws + WTIH_OFF, ws + BIAS_OFF, ws + C_OFF, ws + HL_OFF,
                                        ws + PM_OFF, ws + PDEN_OFF, ws + PNUM_OFF, step);
    attn_kernel<<<NB * BPS, 256, 0, stream>>>((const short*)(ws + H2B_OFF), ws + HL_OFF, segb,
                                              ws + PM_OFF, ws + PDEN_OFF, ws + PNUM_OFF);
  }
  final_kernel<<<26, 256, 0, stream>>>(ws + PM_OFF, ws + PDEN_OFF, ws + PNUM_OFF,
                                       ws + HL_OFF, (float*)d_out);
}